// Round 9
// baseline (1499.636 us; speedup 1.0000x reference)
//
#include <hip/hip_runtime.h>

static constexpr int N_ = 32, V_ = 25, T_ = 64, C_ = 256;
static constexpr int S_ = 3, ST_ = 2, CI_ = 64, K_ = 7;
static constexpr int M_  = N_ * V_ * T_;          // 51200 rows (also N*T*V)
static constexpr int TC_ = T_ * C_;               // 16384
static constexpr int VC_ = V_ * C_;               // 6400
static constexpr long TOT_ = (long)M_ * C_;       // 13,107,200
static constexpr long PLANE_ = 2048L * 1600;      // per-chan QKT plane (ushorts)
static constexpr int TP_ = T_ + 6;                // padded t extent (70)

typedef __bf16 bf16x8 __attribute__((ext_vector_type(8)));
typedef float  f32x4  __attribute__((ext_vector_type(4)));

__device__ __forceinline__ float gelu_f(float x) {
    return 0.5f * x * (1.0f + erff(x * 0.70710678118654752f));
}
__device__ __forceinline__ ushort f2bf(float x) {       // RNE f32 -> bf16 bits
    uint u = __float_as_uint(x);
    u += 0x7fffu + ((u >> 16) & 1u);
    return (ushort)(u >> 16);
}
__device__ __forceinline__ float bf2f(ushort h) { return __uint_as_float((uint)h << 16); }

// physical LDS ushort offset for (row, chunk) with 2-way-free XOR swizzle
__device__ __forceinline__ int lofs(int row, int chunk) {
    return row * 32 + ((chunk ^ ((row >> 1) & 3)) << 3);
}

// async global->LDS 16B copy (LDS dest must be linear in lane order)
__device__ __forceinline__ void gll16(const ushort* g, ushort* l) {
    __builtin_amdgcn_global_load_lds(
        (const __attribute__((address_space(1))) void*)g,
        (__attribute__((address_space(3))) void*)l, 16, 0, 0);
}

// bijective XCD-chunked block swizzle (m204): same-XCD blocks get contiguous ids
__device__ __forceinline__ void xcd_swz(int& bx, int& by) {
    const int gx = gridDim.x;
    const int nwg = gx * gridDim.y;
    const int o = blockIdx.y * gx + blockIdx.x;
    const int q = nwg >> 3, r = nwg & 7;
    const int xcd = o & 7, idx = o >> 3;
    const int id = (xcd < r) ? (xcd * (q + 1) + idx)
                             : (r * (q + 1) + (xcd - r) * q + idx);
    bx = id % gx; by = id / gx;
}

// ---------------- preps --------------------------------------------------------
// all weight conversions in ONE launch (range-dispatched)
__global__ void prep_weights(
    const float* __restrict__ Wqk_s, const float* __restrict__ Wo_s,
    const float* __restrict__ Wff_s, const float* __restrict__ Wqk_t,
    const float* __restrict__ Wo_t,  const float* __restrict__ Wff_t,
    const float* __restrict__ conv_w,
    ushort* __restrict__ qs_h, ushort* __restrict__ qs_l,
    ushort* __restrict__ os_h, ushort* __restrict__ os_l,
    ushort* __restrict__ fs_h, ushort* __restrict__ fs_l,
    ushort* __restrict__ qt_h, ushort* __restrict__ qt_l,
    ushort* __restrict__ ot0_h, ushort* __restrict__ ot0_l,
    ushort* __restrict__ ot1_h, ushort* __restrict__ ot1_l,
    ushort* __restrict__ ft_h, ushort* __restrict__ ft_l,
    ushort* __restrict__ cv_h, ushort* __restrict__ cv_l)
{
    int idx = blockIdx.x * 256 + threadIdx.x;
    float x; ushort *h, *l; int li;
    if (idx < 819200) {
        // transposed [Nc][256] segments: plane[n][k] = W[k*LDW + n]
        const float* W; int base, ldw;
        if      (idx <  98304) { W=Wqk_s; h=qs_h;  l=qs_l;  base=0;      ldw=384; }
        else if (idx < 294912) { W=Wo_s;  h=os_h;  l=os_l;  base=98304;  ldw=768; }
        else if (idx < 360448) { W=Wff_s; h=fs_h;  l=fs_l;  base=294912; ldw=256; }
        else if (idx < 491520) { W=Wqk_t; h=qt_h;  l=qt_l;  base=360448; ldw=512; }
        else if (idx < 622592) { W=Wo_t;  h=ot0_h; l=ot0_l; base=491520; ldw=512; }
        else if (idx < 753664) { W=Wo_t + (long)ST_*C_*C_; h=ot1_h; l=ot1_l; base=622592; ldw=512; }
        else                   { W=Wff_t; h=ft_h;  l=ft_l;  base=753664; ldw=256; }
        li = idx - base;
        int n = li >> 8, k = li & 255;
        x = W[(long)k * ldw + n];
    } else {
        // conv: [kh][o][i] from cw (O,I,K)
        li = idx - 819200;                 // over K*C*C
        int kh = li / (C_ * C_);
        int rem = li % (C_ * C_);
        int o = rem >> 8, i = rem & 255;
        x = conv_w[((long)o * C_ + i) * K_ + kh];
        h = cv_h; l = cv_l;
    }
    ushort hb = f2bf(x);
    h[li] = hb;
    l[li] = f2bf(x - bf2f(hb));
}
__global__ void prep_x(const float* __restrict__ X,
                       ushort* __restrict__ Xh, ushort* __restrict__ Xl) {
    long i = (long)blockIdx.x * 256 + threadIdx.x;
    if (i >= TOT_) return;
    float v = X[i];
    ushort h = f2bf(v);
    Xh[i] = h;
    Xl[i] = f2bf(v - bf2f(h));
}
__global__ void zero_pad(ushort* __restrict__ Zph, ushort* __restrict__ Zpl) {
    int idx = blockIdx.x * 256 + threadIdx.x;        // over N*6*V*C
    if (idx >= N_ * 6 * V_ * C_) return;
    int n = idx / (6 * V_ * C_);
    int rem = idx % (6 * V_ * C_);
    int tpi = rem / (V_ * C_), vc = rem % (V_ * C_);
    int tp = (tpi < 3) ? tpi : (64 + tpi);           // 0,1,2,67,68,69
    long o = ((long)(n * TP_ + tp) * V_) * C_ + vc;
    Zph[o] = 0; Zpl[o] = 0;
}

// ---------------- bf16x3 MFMA GEMM: Out = A @ W (+bias) -----------------------
// A staged via dbuf gll-LDS (32KB only); W fragments loaded straight from
// L2-resident global (k-major plane -> 16B/lane dwordx4, no LDS). Keeps R8's
// stage(k+1)-under-compute(k) overlap without R8's 64KB occupancy cliff.
__global__ __launch_bounds__(256) void gemm_bf(
    const ushort* __restrict__ Agh, const ushort* __restrict__ Agl,
    const ushort* __restrict__ Wh,  const ushort* __restrict__ Wl,
    const float* __restrict__ bias,
    float* __restrict__ Out, int Nc)
{
    __shared__ ushort Ah[2][128 * 32], Al[2][128 * 32];
    int bx, by;  xcd_swz(bx, by);
    const int tid = threadIdx.x;
    const int row0 = by * 128, col0 = bx * 128;
    const int lane = tid & 63;
    const int wid = tid >> 6, wm = wid >> 1, wn = wid & 1;
    const int fr = lane & 15, fc = lane >> 4;
    const int r0 = tid >> 2;
    const int cl0 = (tid & 3) ^ ((r0 >> 1) & 3);
    const int r1 = r0 + 64;
    const int cl1 = (tid & 3) ^ ((r1 >> 1) & 3);
    const long a0off = (long)(row0 + r0) * 256 + cl0 * 8;
    const long a1off = (long)(row0 + r1) * 256 + cl1 * 8;
    const int u0 = tid * 8, u1 = (tid + 256) * 8;
    // per-lane W fragment base: row (col0+wn*64+j*16+fr), k-chunk fc
    const long wofs = (long)(col0 + wn * 64 + fr) * 256 + fc * 8;

    auto stage = [&](int b, int k0) {
        gll16(Agh + a0off + k0, &Ah[b][u0]);  gll16(Agh + a1off + k0, &Ah[b][u1]);
        gll16(Agl + a0off + k0, &Al[b][u0]);  gll16(Agl + a1off + k0, &Al[b][u1]);
    };

    f32x4 acc[4][4] = {};
    stage(0, 0);
    __syncthreads();
    int cur = 0;
    for (int ks = 0; ks < 8; ++ks) {
        const int k0 = ks * 32;
        bf16x8 wh[4], wl[4];
        #pragma unroll
        for (int j = 0; j < 4; ++j) {
            wh[j] = *(const bf16x8*)(Wh + wofs + j * 4096 + k0);
            wl[j] = *(const bf16x8*)(Wl + wofs + j * 4096 + k0);
        }
        if (ks + 1 < 8) stage(cur ^ 1, k0 + 32);   // fly under MFMAs below
        bf16x8 fah[4], fal[4];
        #pragma unroll
        for (int i = 0; i < 4; ++i) {
            int oA = lofs(wm * 64 + i * 16 + fr, fc);
            fah[i] = *(bf16x8*)&Ah[cur][oA];
            fal[i] = *(bf16x8*)&Al[cur][oA];
        }
        #pragma unroll
        for (int j = 0; j < 4; ++j)
            #pragma unroll
            for (int i = 0; i < 4; ++i) {
                acc[i][j] = __builtin_amdgcn_mfma_f32_16x16x32_bf16(fah[i], wh[j], acc[i][j], 0, 0, 0);
                acc[i][j] = __builtin_amdgcn_mfma_f32_16x16x32_bf16(fah[i], wl[j], acc[i][j], 0, 0, 0);
                acc[i][j] = __builtin_amdgcn_mfma_f32_16x16x32_bf16(fal[i], wh[j], acc[i][j], 0, 0, 0);
            }
        __syncthreads();   // next A buffer ready; reads of cur done
        cur ^= 1;
    }
    float bv[4]; int colv[4];
    #pragma unroll
    for (int j = 0; j < 4; ++j) {
        colv[j] = col0 + wn * 64 + j * 16 + fr;
        bv[j] = bias ? bias[colv[j]] : 0.0f;
    }
    #pragma unroll
    for (int i = 0; i < 4; ++i) {
        long rbase = row0 + wm * 64 + i * 16 + fc * 4;
        #pragma unroll
        for (int r = 0; r < 4; ++r) {
            long ob = (rbase + r) * (long)Nc;
            #pragma unroll
            for (int j = 0; j < 4; ++j)
                Out[ob + colv[j]] = acc[i][j][r] + bv[j];
        }
    }
}

// ---------------- conv(7x1 over T) bf16x3 MFMA, same A-dbuf + global-W --------
__global__ __launch_bounds__(256) void conv_bn_gelu(
    const ushort* __restrict__ Zph, const ushort* __restrict__ Zpl, // (N,70,V,C)
    const ushort* __restrict__ Wh, const ushort* __restrict__ Wl,    // [kh][o][i]
    const float* __restrict__ conv_b, const float* __restrict__ bn_g,
    const float* __restrict__ bn_b,  const float* __restrict__ bn_m,
    const float* __restrict__ bn_v,
    float* __restrict__ Out)          // (N,V,T,C)
{
    __shared__ ushort Ah[2][128 * 32], Al[2][128 * 32];
    int bx, by;  xcd_swz(bx, by);
    const int tid = threadIdx.x;
    const int row0 = by * 128, col0 = bx * 128;
    const int lane = tid & 63;
    const int wid = tid >> 6, wm = wid >> 1, wn = wid & 1;
    const int fr = lane & 15, fc = lane >> 4;
    const int r0 = tid >> 2;
    const int cl0 = (tid & 3) ^ ((r0 >> 1) & 3);
    const int r1 = r0 + 64;
    const int cl1 = (tid & 3) ^ ((r1 >> 1) & 3);
    const int m0 = row0 + r0, m1 = row0 + r1;
    const int n0 = m0 / (T_ * V_), q0 = m0 % (T_ * V_);
    const int n1 = m1 / (T_ * V_), q1 = m1 % (T_ * V_);
    const long a0base = ((long)(n0 * TP_ + q0 / V_) * V_ + q0 % V_) * 256 + cl0 * 8;
    const long a1base = ((long)(n1 * TP_ + q1 / V_) * V_ + q1 % V_) * 256 + cl1 * 8;
    const int u0 = tid * 8, u1 = (tid + 256) * 8;
    const long wofs = (long)(col0 + wn * 64 + fr) * 256 + fc * 8;

    auto stage = [&](int b, int kt) {
        const int kh = kt >> 3;
        const long kc = (kt & 7) * 32;
        const long ao = (long)kh * V_ * 256;
        gll16(Zph + a0base + ao + kc, &Ah[b][u0]);
        gll16(Zph + a1base + ao + kc, &Ah[b][u1]);
        gll16(Zpl + a0base + ao + kc, &Al[b][u0]);
        gll16(Zpl + a1base + ao + kc, &Al[b][u1]);
    };

    f32x4 acc[4][4] = {};
    stage(0, 0);
    __syncthreads();
    int cur = 0;
    for (int kt = 0; kt < K_ * 8; ++kt) {     // 56 k-steps of 32
        const int kh = kt >> 3;
        const long wo = (long)kh * 65536 + (kt & 7) * 32;
        bf16x8 wh[4], wl[4];
        #pragma unroll
        for (int j = 0; j < 4; ++j) {
            wh[j] = *(const bf16x8*)(Wh + wofs + j * 4096 + wo);
            wl[j] = *(const bf16x8*)(Wl + wofs + j * 4096 + wo);
        }
        if (kt + 1 < K_ * 8) stage(cur ^ 1, kt + 1);
        bf16x8 fah[4], fal[4];
        #pragma unroll
        for (int i = 0; i < 4; ++i) {
            int oA = lofs(wm * 64 + i * 16 + fr, fc);
            fah[i] = *(bf16x8*)&Ah[cur][oA];
            fal[i] = *(bf16x8*)&Al[cur][oA];
        }
        #pragma unroll
        for (int j = 0; j < 4; ++j)
            #pragma unroll
            for (int i = 0; i < 4; ++i) {
                acc[i][j] = __builtin_amdgcn_mfma_f32_16x16x32_bf16(fah[i], wh[j], acc[i][j], 0, 0, 0);
                acc[i][j] = __builtin_amdgcn_mfma_f32_16x16x32_bf16(fah[i], wl[j], acc[i][j], 0, 0, 0);
                acc[i][j] = __builtin_amdgcn_mfma_f32_16x16x32_bf16(fal[i], wh[j], acc[i][j], 0, 0, 0);
            }
        __syncthreads();
        cur ^= 1;
    }
    float cbv[4], scv[4], shv[4]; int colv[4];
    #pragma unroll
    for (int j = 0; j < 4; ++j) {
        int c = col0 + wn * 64 + j * 16 + fr;
        colv[j] = c;
        cbv[j] = conv_b[c];
        float sc = rsqrtf(bn_v[c] + 1e-5f) * bn_g[c];
        scv[j] = sc;
        shv[j] = bn_b[c] - bn_m[c] * sc;
    }
    #pragma unroll
    for (int i = 0; i < 4; ++i)
        #pragma unroll
        for (int r = 0; r < 4; ++r) {
            int m = row0 + wm * 64 + i * 16 + fc * 4 + r;
            int n = m / (T_ * V_);
            int rem = m % (T_ * V_);
            int t = rem / V_, v = rem % V_;
            long ob = (((long)n * V_ + v) * T_ + t) * C_;
            long pb = ((long)(n * TP_ + t + 3) * V_ + v) * C_;   // residual from planes
            #pragma unroll
            for (int j = 0; j < 4; ++j) {
                float cv = acc[i][j][r] + cbv[j];
                float bn = cv * scv[j] + shv[j];
                float res = bf2f(Zph[pb + colv[j]]) + bf2f(Zpl[pb + colv[j]]);
                Out[ob + colv[j]] = gelu_f(res + bn);
            }
        }
}

// ---------------- small utility kernels ---------------------------------------
__global__ void zero_f32(float* __restrict__ p, int n) {
    int i = blockIdx.x * 256 + threadIdx.x;
    if (i < n) p[i] = 0.0f;
}

// ---------------- spatial attention scores ------------------------------------
__global__ __launch_bounds__(256) void att_s_partial(
    const float* __restrict__ QK,     // (N,V,T,384)
    float* __restrict__ attPre)       // (N,V,V,S) zero-init
{
    const int n = blockIdx.x;
    const int tg = blockIdx.y;        // 0..15, 4 t's each
    __shared__ float lds[V_ * 385];   // 9625 floats (odd stride: no bank alias)
    const int NOUT = V_ * V_ * S_;    // 1875
    float acc[8] = {};
    for (int ttc = 0; ttc < 4; ++ttc) {
        int t = tg * 4 + ttc;
        __syncthreads();
        for (int l = threadIdx.x; l < V_ * 96; l += 256) {
            int v = l / 96, j = (l % 96) * 4;
            float4 q = *(const float4*)&QK[(((long)n * V_ + v) * T_ + t) * 384 + j];
            float* d = &lds[v * 385 + j];
            d[0] = q.x; d[1] = q.y; d[2] = q.z; d[3] = q.w;
        }
        __syncthreads();
        int ai = 0;
        for (int o = threadIdx.x; o < NOUT; o += 256, ++ai) {
            int u = o / (V_ * S_), rem = o % (V_ * S_), v = rem / S_, s = rem % S_;
            const float* qp = &lds[u * 385 + s];
            const float* kp = &lds[v * 385 + S_ + s];
            float sum = 0.f;
            #pragma unroll 8
            for (int ci = 0; ci < CI_; ++ci) sum += qp[ci * 6] * kp[ci * 6];
            acc[ai] += sum;
        }
    }
    int ai = 0;
    for (int o = threadIdx.x; o < NOUT; o += 256, ++ai)
        atomicAdd(&attPre[(long)n * NOUT + o], acc[ai]);
}

__global__ void att_s_final(const float* __restrict__ attPre,
                            const float* __restrict__ alphas,
                            const float* __restrict__ att0,
                            float* __restrict__ attS) {
    int idx = blockIdx.x * 256 + threadIdx.x;
    if (idx >= N_ * V_ * V_ * S_) return;
    int o = idx % (V_ * V_ * S_);
    int s = o % S_;
    attS[idx] = tanhf(attPre[idx] * (1.0f / (CI_ * T_))) * alphas[s] + att0[o];
}

// ---------------- fused spatial mixing ----------------------------------------
__global__ __launch_bounds__(256) void vmix_all(
    const float* __restrict__ G,      // (M, 768)
    const float* __restrict__ attS,   // (N,V,V,S)
    const float* __restrict__ bias,   // (C)
    float* __restrict__ P)            // (N,V,TC)
{
    const int n = blockIdx.y;
    const int t = blockIdx.x;         // 0..63
    const int c = threadIdx.x;        // 0..255
    __shared__ float a[3][V_ * V_];
    for (int l = threadIdx.x; l < V_ * V_ * S_; l += 256) {
        int uv = l / S_, s = l % S_;
        a[s][uv] = attS[((long)n * V_ * V_ + uv) * S_ + s];
    }
    __syncthreads();
    float acc[V_] = {};
    for (int u = 0; u < V_; ++u) {
        const float* g = G + ((long)((n * V_ + u) * T_) + t) * 768 + c;
        float v0 = g[0], v1 = g[256], v2 = g[512];
        const float* a0 = &a[0][u * V_], *a1 = &a[1][u * V_], *a2 = &a[2][u * V_];
        #pragma unroll
        for (int v = 0; v < V_; ++v)
            acc[v] += a0[v] * v0 + a1[v] * v1 + a2[v] * v2;
    }
    const float b = bias[c];
    for (int v = 0; v < V_; ++v)
        P[((long)(n * V_ + v) * T_ + t) * C_ + c] = acc[v] + b;
}

// ---------------- QKT repack: (N,T,V,ci,8chan) f32 -> 8 k-major bf16 planes ---
__global__ void qkt_repack(const float* __restrict__ QKT,
                           ushort* __restrict__ QPh, ushort* __restrict__ QPl) {
    long idx = (long)blockIdx.x * 256 + threadIdx.x;   // over M_*CI_
    if (idx >= (long)M_ * CI_) return;
    int m = (int)(idx >> 6), ci = (int)(idx & 63);
    int n = m / (T_ * V_);
    int rem = m % (T_ * V_);
    int t = rem / V_, v = rem % V_;
    const float* src = QKT + (long)m * 512 + ci * 8;
    float4 s0 = *(const float4*)src;
    float4 s1 = *(const float4*)(src + 4);
    float f[8] = {s0.x, s0.y, s0.z, s0.w, s1.x, s1.y, s1.z, s1.w};
    long rowk = ((long)(n * T_ + t)) * 1600 + v * 64 + ci;
    #pragma unroll
    for (int chan = 0; chan < 8; ++chan) {
        ushort h = f2bf(f[chan]);
        QPh[(long)chan * PLANE_ + rowk] = h;
        QPl[(long)chan * PLANE_ + rowk] = f2bf(f[chan] - bf2f(h));
    }
}

// ---------------- temporal attention scores via bf16x3 MFMA -------------------
__global__ __launch_bounds__(256) void att_t_mfma(
    const ushort* __restrict__ QPh, const ushort* __restrict__ QPl,
    float* __restrict__ part)
{
    const int ks = blockIdx.x, pair = blockIdx.y, n = blockIdx.z;
    const int kbeg = (ks * 50) / 4, kend = ((ks + 1) * 50) / 4;   // 50 k-steps of 32
    __shared__ ushort Qh[64 * 32], Ql[64 * 32], Kh[64 * 32], Kl[64 * 32];
    const int tid = threadIdx.x;
    const int lane = tid & 63;
    const int wid = tid >> 6, wm = wid >> 1, wn = wid & 1;
    const int fr = lane & 15, fc = lane >> 4;
    const int tr = tid >> 2, tc = tid & 3;
    const long rowoff = ((long)n * T_ + tr) * 1600 + tc * 8;
    const ushort* qh_g = QPh + (long)pair * PLANE_ + rowoff;
    const ushort* ql_g = QPl + (long)pair * PLANE_ + rowoff;
    const ushort* kh_g = QPh + (long)(pair + 4) * PLANE_ + rowoff;
    const ushort* kl_g = QPl + (long)(pair + 4) * PLANE_ + rowoff;
    const int la = lofs(tr, tc);

    uint4 pqh = *(const uint4*)(qh_g + kbeg * 32);
    uint4 pql = *(const uint4*)(ql_g + kbeg * 32);
    uint4 pkh = *(const uint4*)(kh_g + kbeg * 32);
    uint4 pkl = *(const uint4*)(kl_g + kbeg * 32);

    f32x4 acc[2][2] = {};
    for (int kstep = kbeg; kstep < kend; ++kstep) {
        __syncthreads();
        *(uint4*)&Qh[la] = pqh;  *(uint4*)&Ql[la] = pql;
        *(uint4*)&Kh[la] = pkh;  *(uint4*)&Kl[la] = pkl;
        __syncthreads();
        if (kstep + 1 < kend) {
            pqh = *(const uint4*)(qh_g + (kstep + 1) * 32);
            pql = *(const uint4*)(ql_g + (kstep + 1) * 32);
            pkh = *(const uint4*)(kh_g + (kstep + 1) * 32);
            pkl = *(const uint4*)(kl_g + (kstep + 1) * 32);
        }
        bf16x8 ah[2], al[2];
        #pragma unroll
        for (int i = 0; i < 2; ++i) {
            int oA = lofs(wm * 32 + i * 16 + fr, fc);
            ah[i] = *(bf16x8*)&Qh[oA];
            al[i] = *(bf16x8*)&Ql[oA];
        }
        #pragma unroll
        for (int j = 0; j < 2; ++j) {
            int oB = lofs(wn * 32 + j * 16 + fr, fc);
            bf16x8 bh = *(bf16x8*)&Kh[oB];
            bf16x8 bl = *(bf16x8*)&Kl[oB];
            #pragma unroll
            for (int i = 0; i < 2; ++i) {
                acc[i][j] = __builtin_amdgcn_mfma_f32_16x16x32_bf16(ah[i], bh, acc[i][j], 0, 0, 0);
                acc[i][j] = __builtin_amdgcn_mfma_f32_16x16x32_bf16(ah[i], bl, acc[i][j], 0, 0, 0);
                acc[i][j] = __builtin_amdgcn_mfma_f32_16x16x32_bf16(al[i], bh, acc[i][j], 0, 0, 0);
            }
        }
    }
    float* pb = part + (((long)ks * N_ + n) * 4 + pair) * 4096;
    #pragma unroll
    for (int i = 0; i < 2; ++i)
        #pragma unroll
        for (int r = 0; r < 4; ++r) {
            int t = wm * 32 + i * 16 + fc * 4 + r;
            #pragma unroll
            for (int j = 0; j < 2; ++j) {
                int q = wn * 32 + j * 16 + fr;
                pb[t * 64 + q] = acc[i][j][r];
            }
        }
}

// ---------------- finish temporal attention -----------------------------------
__global__ void att_t_final(const float* __restrict__ part,
                            const float* __restrict__ alphat_f,
                            const float* __restrict__ alphat_b,
                            float* __restrict__ attF, float* __restrict__ attB) {
    int idx = blockIdx.x * 256 + threadIdx.x;   // N*4*4096
    if (idx >= N_ * 4 * 4096) return;
    int n = idx >> 14;
    int rem = idx & 16383;
    int p = rem >> 12, tq = rem & 4095;
    int t = tq >> 6, q = tq & 63;
    const long stride = (long)N_ * 4 * 4096;
    float sum = 0.f;
    #pragma unroll
    for (int ks = 0; ks < 4; ++ks) sum += part[ks * stride + idx];
    float val = tanhf(sum * (1.0f / (CI_ * V_)));
    if (p < 2) {
        float m = (t >= q) ? 1.0f : 0.0f;
        attF[((long)(n * 2 + p)) * 4096 + tq] = val * alphat_f[p] * m;
    } else {
        float m = (q >= t) ? 1.0f : 0.0f;
        attB[((long)(n * 2 + (p - 2))) * 4096 + tq] = val * alphat_b[p - 2] * m;
    }
}

// ---------------- fused temporal mixing ---------------------------------------
template <bool INIT>
__global__ __launch_bounds__(256) void tmix_all(
    const float* __restrict__ G,      // (M, 512) rows (n*T+t)*V+v
    const float* __restrict__ att,    // (N,2,T,T)
    const float* __restrict__ bias,   // (C) or null
    float* __restrict__ P)            // (N,T,VC)
{
    const int n = blockIdx.y;
    const int col = blockIdx.x * 64 + (threadIdx.x & 63);  // 0..VC-1
    const int ty = threadIdx.x >> 6;                       // 0..3
    const int v = col >> 8, c = col & 255;
    __shared__ float a[2 * T_ * T_];
    for (int l = threadIdx.x; l < 2 * T_ * T_; l += 256)
        a[l] = att[(long)n * 2 * T_ * T_ + l];
    __syncthreads();
    float acc[16] = {};
    for (int t = 0; t < T_; ++t) {
        const float* g = G + ((long)((n * T_ + t) * V_) + v) * 512 + c;
        float v0 = g[0], v1 = g[256];
        const float* ar0 = &a[t * T_ + ty * 16];
        const float* ar1 = ar0 + T_ * T_;
        #pragma unroll
        for (int i = 0; i < 16; ++i) acc[i] += ar0[i] * v0 + ar1[i] * v1;
    }
    for (int i = 0; i < 16; ++i) {
        int q = ty * 16 + i;
        long idx = ((long)n * T_ + q) * VC_ + col;
        if (INIT) P[idx] = acc[i] + bias[c];
        else      P[idx] += acc[i];
    }
}

// ---------------- LayerNorm kernels -------------------------------------------
#define LN_STATS(PBASE, L)                                                     \
    float s = 0.f, ss = 0.f;                                                   \
    for (int i = threadIdx.x; i < L; i += 256) { float a = (PBASE)[i]; s += a; ss += a * a; } \
    __shared__ float rs[4], rss[4];                                            \
    _Pragma("unroll")                                                          \
    for (int off = 32; off > 0; off >>= 1) { s += __shfl_down(s, off); ss += __shfl_down(ss, off); } \
    if ((threadIdx.x & 63) == 0) { rs[threadIdx.x >> 6] = s; rss[threadIdx.x >> 6] = ss; } \
    __syncthreads();                                                           \
    s = rs[0] + rs[1] + rs[2] + rs[3];                                         \
    ss = rss[0] + rss[1] + rss[2] + rss[3];                                    \
    const float mean = s * (1.0f / (L));                                       \
    const float var  = ss * (1.0f / (L)) - mean * mean;                        \
    const float rstd = rsqrtf(var + 1e-5f);

// Y = gelu(x + ln(P)) over (T,C) -> bf16 hi/lo, same layout
__global__ __launch_bounds__(256) void ln_tc_y(
    const float* __restrict__ P, const float* __restrict__ X,
    const float* __restrict__ G, const float* __restrict__ B,
    ushort* __restrict__ Oh, ushort* __restrict__ Ol)
{
    const int g = blockIdx.x;          // n*V+v
    const float* p = P + (long)g * TC_;
    const float* x = X + (long)g * TC_;
    LN_STATS(p, TC_)
    for (int i = threadIdx.x; i < TC_; i += 256) {
        float val = (p[i] - mean) * rstd * G[i] + B[i];
        float r = gelu_f(x[i] + val);
        ushort h = f2bf(r);
        Oh[(long)g * TC_ + i] = h;
        Ol[(long)g * TC_ + i] = f2bf(r - bf2f(h));
    }
}

// YT = gelu(x + ln(P)) over (T,C), transposed to (N,T,V,C) -> bf16 hi/lo ONLY
__global__ __launch_bounds__(256) void ln_tc_yt(
    const float* __restrict__ P, const float* __restrict__ X,
    const float* __restrict__ G, const float* __restrict__ B,
    ushort* __restrict__ Oh, ushort* __restrict__ Ol)
{
    const int g = blockIdx.x;          // n*V+v
    const int n = g / V_, v = g % V_;
    const float* p = P + (long)g * TC_;
    const float* x = X + (long)g * TC_;
    LN_STATS(p, TC_)
    for (int i = threadIdx.x; i < TC_; i += 256) {
        float val = (p[i] - mean) * rstd * G[i] + B[i];
        float r = gelu_f(x[i] + val);
        int t = i >> 8, c = i & 255;
        long o = (((long)n * T_ + t) * V_ + v) * C_ + c;
        ushort h = f2bf(r);
        Oh[o] = h;
        Ol[o] = f2bf(r - bf2f(h));
    }
}

// Z = gelu(yT + ln(P)) over (V,C), residual from YT planes -> bf16 hi/lo
__global__ __launch_bounds__(256) void ln_vc_z(
    const float* __restrict__ P,
    const ushort* __restrict__ Xh, const ushort* __restrict__ Xl,
    const float* __restrict__ G, const float* __restrict__ B,
    ushort* __restrict__ Oh, ushort* __restrict__ Ol)
{
    const int g = blockIdx.x;          // n*T+t
    const float* p = P + (long)g * VC_;
    LN_STATS(p, VC_)
    for (int i = threadIdx.x; i < VC_; i += 256) {
        long o = (long)g * VC_ + i;
        float xr = bf2f(Xh[o]) + bf2f(Xl[o]);
        float val = (p[i] - mean) * rstd * G[i] + B[i];
        float r = gelu_f(xr + val);
        ushort h = f2bf(r);
        Oh[o] = h;
        Ol[o] = f2bf(r - bf2f(h));
    }
}

// Z2 = gelu(yT + ln(P)) over (V,C), residual from YT planes -> padded planes
__global__ __launch_bounds__(256) void ln_vc_z2(
    const float* __restrict__ P,
    const ushort* __restrict__ Xh, const ushort* __restrict__ Xl,
    const float* __restrict__ G, const float* __restrict__ B,
    ushort* __restrict__ Zph, ushort* __restrict__ Zpl)
{
    const int g = blockIdx.x;          // n*T+t
    const int n = g / T_, t = g % T_;
    const float* p = P + (long)g * VC_;
    LN_STATS(p, VC_)
    const long pbase = ((long)(n * TP_ + t + 3) * V_) * C_;
    for (int i = threadIdx.x; i < VC_; i += 256) {
        long o = (long)g * VC_ + i;
        float xr = bf2f(Xh[o]) + bf2f(Xl[o]);
        float val = (p[i] - mean) * rstd * G[i] + B[i];
        float r = gelu_f(xr + val);
        ushort h = f2bf(r);
        Zph[pbase + i] = h;
        Zpl[pbase + i] = f2bf(r - bf2f(h));
    }
}

// ==============================================================================
extern "C" void kernel_launch(void* const* d_in, const int* in_sizes, int n_in,
                              void* d_out, int out_size, void* d_ws, size_t ws_size,
                              hipStream_t stream)
{
    const float* x        = (const float*)d_in[0];
    const float* Wqk_s    = (const float*)d_in[1];
    const float* bqk_s    = (const float*)d_in[2];
    const float* alphas   = (const float*)d_in[3];
    const float* att0s    = (const float*)d_in[4];
    const float* Wo_s     = (const float*)d_in[5];
    const float* bo_s     = (const float*)d_in[6];
    const float* g_os     = (const float*)d_in[7];
    const float* b_os     = (const float*)d_in[8];
    const float* Wff_s    = (const float*)d_in[9];
    const float* bff_s    = (const float*)d_in[10];
    const float* g_ffs    = (const float*)d_in[11];
    const float* b_ffs    = (const float*)d_in[12];
    const float* Wqk_t    = (const float*)d_in[13];
    const float* bqk_t    = (const float*)d_in[14];
    const float* alphat_f = (const float*)d_in[15];
    const float* alphat_b = (const float*)d_in[16];
    const float* Wo_t     = (const float*)d_in[17];
    const float* bo_t     = (const float*)d_in[18];
    const float* g_ot     = (const float*)d_in[19];
    const float* b_ot     = (const float*)d_in[20];
    const float* Wff_t    = (const float*)d_in[21];
    const float* bff_t    = (const float*)d_in[22];
    const float* g_fft    = (const float*)d_in[23];
    const float* b_fft    = (const float*)d_in[24];
    const float* conv_w   = (const float*)d_in[25];
    const float* conv_b   = (const float*)d_in[26];
    const float* bn_g     = (const float*)d_in[27];
    const float* bn_b     = (const float*)d_in[28];
    const float* bn_m     = (const float*)d_in[29];
    const float* bn_v     = (const float*)d_in[30];

    float* Bp  = (float*)d_ws;
    float* R0f = Bp;
    float* R1f = Bp + TOT_;
    float* R2f = Bp + 2 * TOT_;
    float* R3f = Bp + 3 * TOT_;
    float* SM  = Bp + 4 * TOT_;
    float* attPre = SM;                               // 60,000
    float* attS   = attPre + N_*V_*V_*S_;             // 60,000
    float* attF   = attS   + N_*V_*V_*S_;             // 262,144
    float* attB   = attF   + (long)N_*2*T_*T_;        // 262,144
    float* part   = attB   + (long)N_*2*T_*T_;        // 2,097,152
    ushort* wp = (ushort*)(part + 4L*N_*4*4096);
    ushort* qs_h = wp;  wp += 384*256;   ushort* qs_l = wp;  wp += 384*256;
    ushort* os_h = wp;  wp += 768*256;   ushort* os_l = wp;  wp += 768*256;
    ushort* fs_h = wp;  wp += 256*256;   ushort* fs_l = wp;  wp += 256*256;
    ushort* qt_h = wp;  wp += 512*256;   ushort* qt_l = wp;  wp += 512*256;
    ushort* ot0_h= wp;  wp += 512*256;   ushort* ot0_l= wp;  wp += 512*256;
    ushort* ot1_h= wp;  wp += 512*256;   ushort* ot1_l= wp;  wp += 512*256;
    ushort* ft_h = wp;  wp += 256*256;   ushort* ft_l = wp;  wp += 256*256;
    ushort* cv_h = wp;  wp += K_*256*256; ushort* cv_l = wp;

    // activation bf16 aliases (lifetimes annotated)
    ushort* xh  = (ushort*)R3f;  ushort* xl  = xh  + TOT_;   // until os GEMM
    ushort* Yh  = (ushort*)R0f;  ushort* Yl  = Yh  + TOT_;   // until fs GEMM
    ushort* YTh = (ushort*)d_out; ushort* YTl = YTh + TOT_;  // until ln_vc_z2
    ushort* QPh = (ushort*)R2f;  ushort* QPl = (ushort*)R3f; // until att_t_mfma
    ushort* Zh  = (ushort*)R0f;  ushort* Zl  = Zh  + TOT_;   // until ft GEMM
    ushort* Zph = (ushort*)R1f;                               // padded conv src
    ushort* Zpl = Zph + (long)N_ * TP_ * V_ * C_;

    // ---- preps (single weight launch + x planes) ----
    prep_weights<<<4992, 256, 0, stream>>>(
        Wqk_s, Wo_s, Wff_s, Wqk_t, Wo_t, Wff_t, conv_w,
        qs_h, qs_l, os_h, os_l, fs_h, fs_l, qt_h, qt_l,
        ot0_h, ot0_l, ot1_h, ot1_l, ft_h, ft_l, cv_h, cv_l);
    prep_x<<<(int)((TOT_ + 255)/256), 256, 0, stream>>>(x, xh, xl);

    // ---- Stage 1: spatial ----
    gemm_bf<<<dim3(3, 400), 256, 0, stream>>>(xh, xl, qs_h, qs_l, bqk_s, R0f, 384);
    zero_f32<<<(N_*V_*V_*S_ + 255)/256, 256, 0, stream>>>(attPre, N_*V_*V_*S_);
    att_s_partial<<<dim3(N_, 16), 256, 0, stream>>>(R0f, attPre);
    att_s_final<<<(N_*V_*V_*S_ + 255)/256, 256, 0, stream>>>(attPre, alphas, att0s, attS);
    gemm_bf<<<dim3(6, 400), 256, 0, stream>>>(xh, xl, os_h, os_l, nullptr, R0f, 768);
    vmix_all<<<dim3(T_, N_), 256, 0, stream>>>(R0f, attS, bo_s, R3f);
    ln_tc_y<<<N_*V_, 256, 0, stream>>>(R3f, x, g_os, b_os, Yh, Yl);
    gemm_bf<<<dim3(2, 400), 256, 0, stream>>>(Yh, Yl, fs_h, fs_l, bff_s, R1f, 256);
    ln_tc_yt<<<N_*V_, 256, 0, stream>>>(R1f, x, g_ffs, b_ffs, YTh, YTl);

    // ---- Stage 2: temporal ----
    gemm_bf<<<dim3(4, 400), 256, 0, stream>>>(YTh, YTl, qt_h, qt_l, bqk_t, R0f, 512);
    qkt_repack<<<(int)(((long)M_*CI_ + 255)/256), 256, 0, stream>>>(R0f, QPh, QPl);
    att_t_mfma<<<dim3(4, 4, N_), 256, 0, stream>>>(QPh, QPl, part);
    att_t_final<<<(N_*4*4096 + 255)/256, 256, 0, stream>>>(part, alphat_f, alphat_b, attF, attB);
    gemm_bf<<<dim3(4, 400), 256, 0, stream>>>(YTh, YTl, ot0_h, ot0_l, nullptr, R0f, 512);
    tmix_all<true><<<dim3(VC_/64, N_), 256, 0, stream>>>(R0f, attF, bo_t, R2f);
    gemm_bf<<<dim3(4, 400), 256, 0, stream>>>(YTh, YTl, ot1_h, ot1_l, nullptr, R0f, 512);
    tmix_all<false><<<dim3(VC_/64, N_), 256, 0, stream>>>(R0f, attB, nullptr, R2f);
    ln_vc_z<<<N_*T_, 256, 0, stream>>>(R2f, YTh, YTl, g_ot, b_ot, Zh, Zl);
    gemm_bf<<<dim3(2, 400), 256, 0, stream>>>(Zh, Zl, ft_h, ft_l, bff_t, R3f, 256);
    zero_pad<<<(N_*6*V_*C_ + 255)/256, 256, 0, stream>>>(Zph, Zpl);
    ln_vc_z2<<<N_*T_, 256, 0, stream>>>(R3f, YTh, YTl, g_fft, b_fft, Zph, Zpl);

    // ---- Stage 3: conv + BN + gelu + transpose ----
    conv_bn_gelu<<<dim3(2, 400), 256, 0, stream>>>(Zph, Zpl, cv_h, cv_l, conv_b, bn_g, bn_b, bn_m, bn_v, (float*)d_out);
}

// Round 11
// 1253.508 us; speedup vs baseline: 1.1964x; 1.1964x over previous
//
#include <hip/hip_runtime.h>

static constexpr int N_ = 32, V_ = 25, T_ = 64, C_ = 256;
static constexpr int S_ = 3, ST_ = 2, CI_ = 64, K_ = 7;
static constexpr int M_  = N_ * V_ * T_;          // 51200 rows (also N*T*V)
static constexpr int TC_ = T_ * C_;               // 16384
static constexpr int VC_ = V_ * C_;               // 6400
static constexpr long TOT_ = (long)M_ * C_;       // 13,107,200
static constexpr long PLANE_ = 2048L * 1600;      // per-chan QKT plane (ushorts)
static constexpr int TP_ = T_ + 6;                // padded t extent (70)

typedef __bf16 bf16x8 __attribute__((ext_vector_type(8)));
typedef float  f32x4  __attribute__((ext_vector_type(4)));

__device__ __forceinline__ float gelu_f(float x) {
    return 0.5f * x * (1.0f + erff(x * 0.70710678118654752f));
}
__device__ __forceinline__ ushort f2bf(float x) {       // RNE f32 -> bf16 bits
    uint u = __float_as_uint(x);
    u += 0x7fffu + ((u >> 16) & 1u);
    return (ushort)(u >> 16);
}
__device__ __forceinline__ float bf2f(ushort h) { return __uint_as_float((uint)h << 16); }

// physical LDS ushort offset for (row, chunk) with 2-way-free XOR swizzle
__device__ __forceinline__ int lofs(int row, int chunk) {
    return row * 32 + ((chunk ^ ((row >> 1) & 3)) << 3);
}

// async global->LDS 16B copy (LDS dest must be linear in lane order)
__device__ __forceinline__ void gll16(const ushort* g, ushort* l) {
    __builtin_amdgcn_global_load_lds(
        (const __attribute__((address_space(1))) void*)g,
        (__attribute__((address_space(3))) void*)l, 16, 0, 0);
}

// bijective XCD-chunked block swizzle (m204): same-XCD blocks get contiguous ids
__device__ __forceinline__ void xcd_swz(int& bx, int& by) {
    const int gx = gridDim.x;
    const int nwg = gx * gridDim.y;
    const int o = blockIdx.y * gx + blockIdx.x;
    const int q = nwg >> 3, r = nwg & 7;
    const int xcd = o & 7, idx = o >> 3;
    const int id = (xcd < r) ? (xcd * (q + 1) + idx)
                             : (r * (q + 1) + (xcd - r) * q + idx);
    bx = id % gx; by = id / gx;
}

// ---------------- preps --------------------------------------------------------
// all weight conversions in ONE launch (range-dispatched)
__global__ void prep_weights(
    const float* __restrict__ Wqk_s, const float* __restrict__ Wo_s,
    const float* __restrict__ Wff_s, const float* __restrict__ Wqk_t,
    const float* __restrict__ Wo_t,  const float* __restrict__ Wff_t,
    const float* __restrict__ conv_w,
    ushort* __restrict__ qs_h, ushort* __restrict__ qs_l,
    ushort* __restrict__ os_h, ushort* __restrict__ os_l,
    ushort* __restrict__ fs_h, ushort* __restrict__ fs_l,
    ushort* __restrict__ qt_h, ushort* __restrict__ qt_l,
    ushort* __restrict__ ot0_h, ushort* __restrict__ ot0_l,
    ushort* __restrict__ ot1_h, ushort* __restrict__ ot1_l,
    ushort* __restrict__ ft_h, ushort* __restrict__ ft_l,
    ushort* __restrict__ cv_h, ushort* __restrict__ cv_l)
{
    int idx = blockIdx.x * 256 + threadIdx.x;
    float x; ushort *h, *l; int li;
    if (idx < 819200) {
        // transposed [Nc][256] segments: plane[n][k] = W[k*LDW + n]
        const float* W; int base, ldw;
        if      (idx <  98304) { W=Wqk_s; h=qs_h;  l=qs_l;  base=0;      ldw=384; }
        else if (idx < 294912) { W=Wo_s;  h=os_h;  l=os_l;  base=98304;  ldw=768; }
        else if (idx < 360448) { W=Wff_s; h=fs_h;  l=fs_l;  base=294912; ldw=256; }
        else if (idx < 491520) { W=Wqk_t; h=qt_h;  l=qt_l;  base=360448; ldw=512; }
        else if (idx < 622592) { W=Wo_t;  h=ot0_h; l=ot0_l; base=491520; ldw=512; }
        else if (idx < 753664) { W=Wo_t + (long)ST_*C_*C_; h=ot1_h; l=ot1_l; base=622592; ldw=512; }
        else                   { W=Wff_t; h=ft_h;  l=ft_l;  base=753664; ldw=256; }
        li = idx - base;
        int n = li >> 8, k = li & 255;
        x = W[(long)k * ldw + n];
    } else {
        // conv: [kh][o][i] from cw (O,I,K)
        li = idx - 819200;                 // over K*C*C
        int kh = li / (C_ * C_);
        int rem = li % (C_ * C_);
        int o = rem >> 8, i = rem & 255;
        x = conv_w[((long)o * C_ + i) * K_ + kh];
        h = cv_h; l = cv_l;
    }
    ushort hb = f2bf(x);
    h[li] = hb;
    l[li] = f2bf(x - bf2f(hb));
}
__global__ void prep_x(const float* __restrict__ X,
                       ushort* __restrict__ Xh, ushort* __restrict__ Xl) {
    long i = (long)blockIdx.x * 256 + threadIdx.x;
    if (i >= TOT_) return;
    float v = X[i];
    ushort h = f2bf(v);
    Xh[i] = h;
    Xl[i] = f2bf(v - bf2f(h));
}
__global__ void zero_pad(ushort* __restrict__ Zph, ushort* __restrict__ Zpl) {
    int idx = blockIdx.x * 256 + threadIdx.x;        // over N*6*V*C
    if (idx >= N_ * 6 * V_ * C_) return;
    int n = idx / (6 * V_ * C_);
    int rem = idx % (6 * V_ * C_);
    int tpi = rem / (V_ * C_), vc = rem % (V_ * C_);
    int tp = (tpi < 3) ? tpi : (64 + tpi);           // 0,1,2,67,68,69
    long o = ((long)(n * TP_ + tp) * V_) * C_ + vc;
    Zph[o] = 0; Zpl[o] = 0;
}

// ---------------- bf16x3 MFMA GEMM: Out = A @ W (+bias), gll staging ----------
// R7 structure (measured best: conv 194us / MfmaUtil 30%): single-buffer LDS
// (32KB -> 3+ blocks/CU), gll for BOTH operands, 2 barriers per k-step.
// R8 (64KB dbuf) and R9 (global-W) both measured slower — do not repeat.
__global__ __launch_bounds__(256) void gemm_bf(
    const ushort* __restrict__ Agh, const ushort* __restrict__ Agl,
    const ushort* __restrict__ Wh,  const ushort* __restrict__ Wl,
    const float* __restrict__ bias,
    float* __restrict__ Out, int Nc)
{
    __shared__ ushort Ah[128 * 32], Al[128 * 32], Bh[128 * 32], Bl[128 * 32];
    int bx, by;  xcd_swz(bx, by);
    const int tid = threadIdx.x;
    const int row0 = by * 128, col0 = bx * 128;
    const int lane = tid & 63;
    const int wid = tid >> 6, wm = wid >> 1, wn = wid & 1;
    const int fr = lane & 15, fc = lane >> 4;
    // staging: unit u holds (row=u>>2, phys chunk=u&3); source uses logical chunk
    const int r0 = tid >> 2;
    const int cl0 = (tid & 3) ^ ((r0 >> 1) & 3);
    const int r1 = r0 + 64;
    const int cl1 = (tid & 3) ^ ((r1 >> 1) & 3);
    const long a0off = (long)(row0 + r0) * 256 + cl0 * 8;
    const long a1off = (long)(row0 + r1) * 256 + cl1 * 8;
    const long w0off = (long)(col0 + r0) * 256 + cl0 * 8;
    const long w1off = (long)(col0 + r1) * 256 + cl1 * 8;
    ushort* dA0 = &Ah[tid * 8];         ushort* dA1 = &Ah[(tid + 256) * 8];
    ushort* dL0 = &Al[tid * 8];         ushort* dL1 = &Al[(tid + 256) * 8];
    ushort* dB0 = &Bh[tid * 8];         ushort* dB1 = &Bh[(tid + 256) * 8];
    ushort* dM0 = &Bl[tid * 8];         ushort* dM1 = &Bl[(tid + 256) * 8];

    f32x4 acc[4][4] = {};
    for (int k0 = 0; k0 < 256; k0 += 32) {
        __syncthreads();
        gll16(Agh + a0off + k0, dA0);  gll16(Agh + a1off + k0, dA1);
        gll16(Agl + a0off + k0, dL0);  gll16(Agl + a1off + k0, dL1);
        gll16(Wh  + w0off + k0, dB0);  gll16(Wh  + w1off + k0, dB1);
        gll16(Wl  + w0off + k0, dM0);  gll16(Wl  + w1off + k0, dM1);
        __syncthreads();
        bf16x8 fah[4], fal[4];
        #pragma unroll
        for (int i = 0; i < 4; ++i) {
            int oA = lofs(wm * 64 + i * 16 + fr, fc);
            fah[i] = *(bf16x8*)&Ah[oA];
            fal[i] = *(bf16x8*)&Al[oA];
        }
        #pragma unroll
        for (int j = 0; j < 4; ++j) {
            int oW = lofs(wn * 64 + j * 16 + fr, fc);
            bf16x8 wh = *(bf16x8*)&Bh[oW];
            bf16x8 wl = *(bf16x8*)&Bl[oW];
            #pragma unroll
            for (int i = 0; i < 4; ++i) {
                acc[i][j] = __builtin_amdgcn_mfma_f32_16x16x32_bf16(fah[i], wh, acc[i][j], 0, 0, 0);
                acc[i][j] = __builtin_amdgcn_mfma_f32_16x16x32_bf16(fah[i], wl, acc[i][j], 0, 0, 0);
                acc[i][j] = __builtin_amdgcn_mfma_f32_16x16x32_bf16(fal[i], wh, acc[i][j], 0, 0, 0);
            }
        }
    }
    float bv[4]; int colv[4];
    #pragma unroll
    for (int j = 0; j < 4; ++j) {
        colv[j] = col0 + wn * 64 + j * 16 + fr;
        bv[j] = bias ? bias[colv[j]] : 0.0f;
    }
    #pragma unroll
    for (int i = 0; i < 4; ++i) {
        long rbase = row0 + wm * 64 + i * 16 + fc * 4;
        #pragma unroll
        for (int r = 0; r < 4; ++r) {
            long ob = (rbase + r) * (long)Nc;
            #pragma unroll
            for (int j = 0; j < 4; ++j)
                Out[ob + colv[j]] = acc[i][j][r] + bv[j];
        }
    }
}

// ---------------- conv(7x1 over T) bf16x3 MFMA from padded planes -------------
// R7 structure (single-buffer gll, measured 194us).
__global__ __launch_bounds__(256) void conv_bn_gelu(
    const ushort* __restrict__ Zph, const ushort* __restrict__ Zpl, // (N,70,V,C)
    const ushort* __restrict__ Wh, const ushort* __restrict__ Wl,    // [kh][o][i]
    const float* __restrict__ conv_b, const float* __restrict__ bn_g,
    const float* __restrict__ bn_b,  const float* __restrict__ bn_m,
    const float* __restrict__ bn_v,
    float* __restrict__ Out)          // (N,V,T,C)
{
    __shared__ ushort Ah[128 * 32], Al[128 * 32], Bh[128 * 32], Bl[128 * 32];
    int bx, by;  xcd_swz(bx, by);
    const int tid = threadIdx.x;
    const int row0 = by * 128, col0 = bx * 128;
    const int lane = tid & 63;
    const int wid = tid >> 6, wm = wid >> 1, wn = wid & 1;
    const int fr = lane & 15, fc = lane >> 4;
    const int r0 = tid >> 2;
    const int cl0 = (tid & 3) ^ ((r0 >> 1) & 3);
    const int r1 = r0 + 64;
    const int cl1 = (tid & 3) ^ ((r1 >> 1) & 3);
    const int m0 = row0 + r0, m1 = row0 + r1;
    const int n0 = m0 / (T_ * V_), q0 = m0 % (T_ * V_);
    const int n1 = m1 / (T_ * V_), q1 = m1 % (T_ * V_);
    // padded base at tap 0 (t index t+0 in padded space = t-3 unpadded)
    const long a0base = ((long)(n0 * TP_ + q0 / V_) * V_ + q0 % V_) * 256 + cl0 * 8;
    const long a1base = ((long)(n1 * TP_ + q1 / V_) * V_ + q1 % V_) * 256 + cl1 * 8;
    const long w0base = (long)(col0 + r0) * 256 + cl0 * 8;
    const long w1base = (long)(col0 + r1) * 256 + cl1 * 8;
    ushort* dA0 = &Ah[tid * 8];         ushort* dA1 = &Ah[(tid + 256) * 8];
    ushort* dL0 = &Al[tid * 8];         ushort* dL1 = &Al[(tid + 256) * 8];
    ushort* dB0 = &Bh[tid * 8];         ushort* dB1 = &Bh[(tid + 256) * 8];
    ushort* dM0 = &Bl[tid * 8];         ushort* dM1 = &Bl[(tid + 256) * 8];

    f32x4 acc[4][4] = {};
    for (int kt = 0; kt < K_ * 8; ++kt) {     // 56 k-steps of 32
        const int kh = kt >> 3;
        const long kc = (kt & 7) * 32;
        const long ao = (long)kh * V_ * 256;
        const long wo = (long)kh * 65536 + kc;
        __syncthreads();
        gll16(Zph + a0base + ao + kc, dA0);  gll16(Zph + a1base + ao + kc, dA1);
        gll16(Zpl + a0base + ao + kc, dL0);  gll16(Zpl + a1base + ao + kc, dL1);
        gll16(Wh + w0base + wo, dB0);        gll16(Wh + w1base + wo, dB1);
        gll16(Wl + w0base + wo, dM0);        gll16(Wl + w1base + wo, dM1);
        __syncthreads();
        bf16x8 fah[4], fal[4];
        #pragma unroll
        for (int i = 0; i < 4; ++i) {
            int oA = lofs(wm * 64 + i * 16 + fr, fc);
            fah[i] = *(bf16x8*)&Ah[oA];
            fal[i] = *(bf16x8*)&Al[oA];
        }
        #pragma unroll
        for (int j = 0; j < 4; ++j) {
            int oW = lofs(wn * 64 + j * 16 + fr, fc);
            bf16x8 wh = *(bf16x8*)&Bh[oW];
            bf16x8 wl = *(bf16x8*)&Bl[oW];
            #pragma unroll
            for (int i = 0; i < 4; ++i) {
                acc[i][j] = __builtin_amdgcn_mfma_f32_16x16x32_bf16(fah[i], wh, acc[i][j], 0, 0, 0);
                acc[i][j] = __builtin_amdgcn_mfma_f32_16x16x32_bf16(fah[i], wl, acc[i][j], 0, 0, 0);
                acc[i][j] = __builtin_amdgcn_mfma_f32_16x16x32_bf16(fal[i], wh, acc[i][j], 0, 0, 0);
            }
        }
    }
    float cbv[4], scv[4], shv[4]; int colv[4];
    #pragma unroll
    for (int j = 0; j < 4; ++j) {
        int c = col0 + wn * 64 + j * 16 + fr;
        colv[j] = c;
        cbv[j] = conv_b[c];
        float sc = rsqrtf(bn_v[c] + 1e-5f) * bn_g[c];
        scv[j] = sc;
        shv[j] = bn_b[c] - bn_m[c] * sc;
    }
    #pragma unroll
    for (int i = 0; i < 4; ++i)
        #pragma unroll
        for (int r = 0; r < 4; ++r) {
            int m = row0 + wm * 64 + i * 16 + fc * 4 + r;
            int n = m / (T_ * V_);
            int rem = m % (T_ * V_);
            int t = rem / V_, v = rem % V_;
            long ob = (((long)n * V_ + v) * T_ + t) * C_;
            long pb = ((long)(n * TP_ + t + 3) * V_ + v) * C_;   // residual from planes
            #pragma unroll
            for (int j = 0; j < 4; ++j) {
                float cv = acc[i][j][r] + cbv[j];
                float bn = cv * scv[j] + shv[j];
                float res = bf2f(Zph[pb + colv[j]]) + bf2f(Zpl[pb + colv[j]]);
                Out[ob + colv[j]] = gelu_f(res + bn);
            }
        }
}

// ---------------- small utility kernels ---------------------------------------
__global__ void zero_f32(float* __restrict__ p, int n) {
    int i = blockIdx.x * 256 + threadIdx.x;
    if (i < n) p[i] = 0.0f;
}

// ---------------- spatial attention scores ------------------------------------
__global__ __launch_bounds__(256) void att_s_partial(
    const float* __restrict__ QK,     // (N,V,T,384)
    float* __restrict__ attPre)       // (N,V,V,S) zero-init
{
    const int n = blockIdx.x;
    const int tg = blockIdx.y;        // 0..15, 4 t's each
    __shared__ float lds[V_ * 385];   // 9625 floats (odd stride: no bank alias)
    const int NOUT = V_ * V_ * S_;    // 1875
    float acc[8] = {};
    for (int ttc = 0; ttc < 4; ++ttc) {
        int t = tg * 4 + ttc;
        __syncthreads();
        for (int l = threadIdx.x; l < V_ * 96; l += 256) {
            int v = l / 96, j = (l % 96) * 4;
            float4 q = *(const float4*)&QK[(((long)n * V_ + v) * T_ + t) * 384 + j];
            float* d = &lds[v * 385 + j];
            d[0] = q.x; d[1] = q.y; d[2] = q.z; d[3] = q.w;
        }
        __syncthreads();
        int ai = 0;
        for (int o = threadIdx.x; o < NOUT; o += 256, ++ai) {
            int u = o / (V_ * S_), rem = o % (V_ * S_), v = rem / S_, s = rem % S_;
            const float* qp = &lds[u * 385 + s];
            const float* kp = &lds[v * 385 + S_ + s];
            float sum = 0.f;
            #pragma unroll 8
            for (int ci = 0; ci < CI_; ++ci) sum += qp[ci * 6] * kp[ci * 6];
            acc[ai] += sum;
        }
    }
    int ai = 0;
    for (int o = threadIdx.x; o < NOUT; o += 256, ++ai)
        atomicAdd(&attPre[(long)n * NOUT + o], acc[ai]);
}

__global__ void att_s_final(const float* __restrict__ attPre,
                            const float* __restrict__ alphas,
                            const float* __restrict__ att0,
                            float* __restrict__ attS) {
    int idx = blockIdx.x * 256 + threadIdx.x;
    if (idx >= N_ * V_ * V_ * S_) return;
    int o = idx % (V_ * V_ * S_);
    int s = o % S_;
    attS[idx] = tanhf(attPre[idx] * (1.0f / (CI_ * T_))) * alphas[s] + att0[o];
}

// ---------------- fused spatial mixing ----------------------------------------
__global__ __launch_bounds__(256) void vmix_all(
    const float* __restrict__ G,      // (M, 768)
    const float* __restrict__ attS,   // (N,V,V,S)
    const float* __restrict__ bias,   // (C)
    float* __restrict__ P)            // (N,V,TC)
{
    const int n = blockIdx.y;
    const int t = blockIdx.x;         // 0..63
    const int c = threadIdx.x;        // 0..255
    __shared__ float a[3][V_ * V_];
    for (int l = threadIdx.x; l < V_ * V_ * S_; l += 256) {
        int uv = l / S_, s = l % S_;
        a[s][uv] = attS[((long)n * V_ * V_ + uv) * S_ + s];
    }
    __syncthreads();
    float acc[V_] = {};
    for (int u = 0; u < V_; ++u) {
        const float* g = G + ((long)((n * V_ + u) * T_) + t) * 768 + c;
        float v0 = g[0], v1 = g[256], v2 = g[512];
        const float* a0 = &a[0][u * V_], *a1 = &a[1][u * V_], *a2 = &a[2][u * V_];
        #pragma unroll
        for (int v = 0; v < V_; ++v)
            acc[v] += a0[v] * v0 + a1[v] * v1 + a2[v] * v2;
    }
    const float b = bias[c];
    for (int v = 0; v < V_; ++v)
        P[((long)(n * V_ + v) * T_ + t) * C_ + c] = acc[v] + b;
}

// ---------------- QKT repack: (N,T,V,ci,8chan) f32 -> 8 k-major bf16 planes ---
__global__ void qkt_repack(const float* __restrict__ QKT,
                           ushort* __restrict__ QPh, ushort* __restrict__ QPl) {
    long idx = (long)blockIdx.x * 256 + threadIdx.x;   // over M_*CI_
    if (idx >= (long)M_ * CI_) return;
    int m = (int)(idx >> 6), ci = (int)(idx & 63);
    int n = m / (T_ * V_);
    int rem = m % (T_ * V_);
    int t = rem / V_, v = rem % V_;
    const float* src = QKT + (long)m * 512 + ci * 8;
    float4 s0 = *(const float4*)src;
    float4 s1 = *(const float4*)(src + 4);
    float f[8] = {s0.x, s0.y, s0.z, s0.w, s1.x, s1.y, s1.z, s1.w};
    long rowk = ((long)(n * T_ + t)) * 1600 + v * 64 + ci;
    #pragma unroll
    for (int chan = 0; chan < 8; ++chan) {
        ushort h = f2bf(f[chan]);
        QPh[(long)chan * PLANE_ + rowk] = h;
        QPl[(long)chan * PLANE_ + rowk] = f2bf(f[chan] - bf2f(h));
    }
}

// ---------------- temporal attention scores via bf16x3 MFMA -------------------
__global__ __launch_bounds__(256) void att_t_mfma(
    const ushort* __restrict__ QPh, const ushort* __restrict__ QPl,
    float* __restrict__ part)
{
    const int ks = blockIdx.x, pair = blockIdx.y, n = blockIdx.z;
    const int kbeg = (ks * 50) / 4, kend = ((ks + 1) * 50) / 4;   // 50 k-steps of 32
    __shared__ ushort Qh[64 * 32], Ql[64 * 32], Kh[64 * 32], Kl[64 * 32];
    const int tid = threadIdx.x;
    const int lane = tid & 63;
    const int wid = tid >> 6, wm = wid >> 1, wn = wid & 1;
    const int fr = lane & 15, fc = lane >> 4;
    const int tr = tid >> 2, tc = tid & 3;
    const long rowoff = ((long)n * T_ + tr) * 1600 + tc * 8;
    const ushort* qh_g = QPh + (long)pair * PLANE_ + rowoff;
    const ushort* ql_g = QPl + (long)pair * PLANE_ + rowoff;
    const ushort* kh_g = QPh + (long)(pair + 4) * PLANE_ + rowoff;
    const ushort* kl_g = QPl + (long)(pair + 4) * PLANE_ + rowoff;
    const int la = lofs(tr, tc);

    uint4 pqh = *(const uint4*)(qh_g + kbeg * 32);
    uint4 pql = *(const uint4*)(ql_g + kbeg * 32);
    uint4 pkh = *(const uint4*)(kh_g + kbeg * 32);
    uint4 pkl = *(const uint4*)(kl_g + kbeg * 32);

    f32x4 acc[2][2] = {};
    for (int kstep = kbeg; kstep < kend; ++kstep) {
        __syncthreads();
        *(uint4*)&Qh[la] = pqh;  *(uint4*)&Ql[la] = pql;
        *(uint4*)&Kh[la] = pkh;  *(uint4*)&Kl[la] = pkl;
        __syncthreads();
        if (kstep + 1 < kend) {
            pqh = *(const uint4*)(qh_g + (kstep + 1) * 32);
            pql = *(const uint4*)(ql_g + (kstep + 1) * 32);
            pkh = *(const uint4*)(kh_g + (kstep + 1) * 32);
            pkl = *(const uint4*)(kl_g + (kstep + 1) * 32);
        }
        bf16x8 ah[2], al[2];
        #pragma unroll
        for (int i = 0; i < 2; ++i) {
            int oA = lofs(wm * 32 + i * 16 + fr, fc);
            ah[i] = *(bf16x8*)&Qh[oA];
            al[i] = *(bf16x8*)&Ql[oA];
        }
        #pragma unroll
        for (int j = 0; j < 2; ++j) {
            int oB = lofs(wn * 32 + j * 16 + fr, fc);
            bf16x8 bh = *(bf16x8*)&Kh[oB];
            bf16x8 bl = *(bf16x8*)&Kl[oB];
            #pragma unroll
            for (int i = 0; i < 2; ++i) {
                acc[i][j] = __builtin_amdgcn_mfma_f32_16x16x32_bf16(ah[i], bh, acc[i][j], 0, 0, 0);
                acc[i][j] = __builtin_amdgcn_mfma_f32_16x16x32_bf16(ah[i], bl, acc[i][j], 0, 0, 0);
                acc[i][j] = __builtin_amdgcn_mfma_f32_16x16x32_bf16(al[i], bh, acc[i][j], 0, 0, 0);
            }
        }
    }
    float* pb = part + (((long)ks * N_ + n) * 4 + pair) * 4096;
    #pragma unroll
    for (int i = 0; i < 2; ++i)
        #pragma unroll
        for (int r = 0; r < 4; ++r) {
            int t = wm * 32 + i * 16 + fc * 4 + r;
            #pragma unroll
            for (int j = 0; j < 2; ++j) {
                int q = wn * 32 + j * 16 + fr;
                pb[t * 64 + q] = acc[i][j][r];
            }
        }
}

// ---------------- finish temporal attention -----------------------------------
__global__ void att_t_final(const float* __restrict__ part,
                            const float* __restrict__ alphat_f,
                            const float* __restrict__ alphat_b,
                            float* __restrict__ attF, float* __restrict__ attB) {
    int idx = blockIdx.x * 256 + threadIdx.x;   // N*4*4096
    if (idx >= N_ * 4 * 4096) return;
    int n = idx >> 14;
    int rem = idx & 16383;
    int p = rem >> 12, tq = rem & 4095;
    int t = tq >> 6, q = tq & 63;
    const long stride = (long)N_ * 4 * 4096;
    float sum = 0.f;
    #pragma unroll
    for (int ks = 0; ks < 4; ++ks) sum += part[ks * stride + idx];
    float val = tanhf(sum * (1.0f / (CI_ * V_)));
    if (p < 2) {
        float m = (t >= q) ? 1.0f : 0.0f;
        attF[((long)(n * 2 + p)) * 4096 + tq] = val * alphat_f[p] * m;
    } else {
        float m = (q >= t) ? 1.0f : 0.0f;
        attB[((long)(n * 2 + (p - 2))) * 4096 + tq] = val * alphat_b[p - 2] * m;
    }
}

// ---------------- fused temporal mixing ---------------------------------------
template <bool INIT>
__global__ __launch_bounds__(256) void tmix_all(
    const float* __restrict__ G,      // (M, 512) rows (n*T+t)*V+v
    const float* __restrict__ att,    // (N,2,T,T)
    const float* __restrict__ bias,   // (C) or null
    float* __restrict__ P)            // (N,T,VC)
{
    const int n = blockIdx.y;
    const int col = blockIdx.x * 64 + (threadIdx.x & 63);  // 0..VC-1
    const int ty = threadIdx.x >> 6;                       // 0..3
    const int v = col >> 8, c = col & 255;
    __shared__ float a[2 * T_ * T_];
    for (int l = threadIdx.x; l < 2 * T_ * T_; l += 256)
        a[l] = att[(long)n * 2 * T_ * T_ + l];
    __syncthreads();
    float acc[16] = {};
    for (int t = 0; t < T_; ++t) {
        const float* g = G + ((long)((n * T_ + t) * V_) + v) * 512 + c;
        float v0 = g[0], v1 = g[256];
        const float* ar0 = &a[t * T_ + ty * 16];
        const float* ar1 = ar0 + T_ * T_;
        #pragma unroll
        for (int i = 0; i < 16; ++i) acc[i] += ar0[i] * v0 + ar1[i] * v1;
    }
    for (int i = 0; i < 16; ++i) {
        int q = ty * 16 + i;
        long idx = ((long)n * T_ + q) * VC_ + col;
        if (INIT) P[idx] = acc[i] + bias[c];
        else      P[idx] += acc[i];
    }
}

// ---------------- LayerNorm kernels -------------------------------------------
#define LN_STATS(PBASE, L)                                                     \
    float s = 0.f, ss = 0.f;                                                   \
    for (int i = threadIdx.x; i < L; i += 256) { float a = (PBASE)[i]; s += a; ss += a * a; } \
    __shared__ float rs[4], rss[4];                                            \
    _Pragma("unroll")                                                          \
    for (int off = 32; off > 0; off >>= 1) { s += __shfl_down(s, off); ss += __shfl_down(ss, off); } \
    if ((threadIdx.x & 63) == 0) { rs[threadIdx.x >> 6] = s; rss[threadIdx.x >> 6] = ss; } \
    __syncthreads();                                                           \
    s = rs[0] + rs[1] + rs[2] + rs[3];                                         \
    ss = rss[0] + rss[1] + rss[2] + rss[3];                                    \
    const float mean = s * (1.0f / (L));                                       \
    const float var  = ss * (1.0f / (L)) - mean * mean;                        \
    const float rstd = rsqrtf(var + 1e-5f);

// Y = gelu(x + ln(P)) over (T,C) -> bf16 hi/lo, same layout
__global__ __launch_bounds__(256) void ln_tc_y(
    const float* __restrict__ P, const float* __restrict__ X,
    const float* __restrict__ G, const float* __restrict__ B,
    ushort* __restrict__ Oh, ushort* __restrict__ Ol)
{
    const int g = blockIdx.x;          // n*V+v
    const float* p = P + (long)g * TC_;
    const float* x = X + (long)g * TC_;
    LN_STATS(p, TC_)
    for (int i = threadIdx.x; i < TC_; i += 256) {
        float val = (p[i] - mean) * rstd * G[i] + B[i];
        float r = gelu_f(x[i] + val);
        ushort h = f2bf(r);
        Oh[(long)g * TC_ + i] = h;
        Ol[(long)g * TC_ + i] = f2bf(r - bf2f(h));
    }
}

// YT = gelu(x + ln(P)) over (T,C), transposed to (N,T,V,C) -> bf16 hi/lo ONLY
__global__ __launch_bounds__(256) void ln_tc_yt(
    const float* __restrict__ P, const float* __restrict__ X,
    const float* __restrict__ G, const float* __restrict__ B,
    ushort* __restrict__ Oh, ushort* __restrict__ Ol)
{
    const int g = blockIdx.x;          // n*V+v
    const int n = g / V_, v = g % V_;
    const float* p = P + (long)g * TC_;
    const float* x = X + (long)g * TC_;
    LN_STATS(p, TC_)
    for (int i = threadIdx.x; i < TC_; i += 256) {
        float val = (p[i] - mean) * rstd * G[i] + B[i];
        float r = gelu_f(x[i] + val);
        int t = i >> 8, c = i & 255;
        long o = (((long)n * T_ + t) * V_ + v) * C_ + c;
        ushort h = f2bf(r);
        Oh[o] = h;
        Ol[o] = f2bf(r - bf2f(h));
    }
}

// Z = gelu(yT + ln(P)) over (V,C), residual from YT planes -> bf16 hi/lo
__global__ __launch_bounds__(256) void ln_vc_z(
    const float* __restrict__ P,
    const ushort* __restrict__ Xh, const ushort* __restrict__ Xl,
    const float* __restrict__ G, const float* __restrict__ B,
    ushort* __restrict__ Oh, ushort* __restrict__ Ol)
{
    const int g = blockIdx.x;          // n*T+t
    const float* p = P + (long)g * VC_;
    LN_STATS(p, VC_)
    for (int i = threadIdx.x; i < VC_; i += 256) {
        long o = (long)g * VC_ + i;
        float xr = bf2f(Xh[o]) + bf2f(Xl[o]);
        float val = (p[i] - mean) * rstd * G[i] + B[i];
        float r = gelu_f(xr + val);
        ushort h = f2bf(r);
        Oh[o] = h;
        Ol[o] = f2bf(r - bf2f(h));
    }
}

// Z2 = gelu(yT + ln(P)) over (V,C), residual from YT planes -> padded planes
__global__ __launch_bounds__(256) void ln_vc_z2(
    const float* __restrict__ P,
    const ushort* __restrict__ Xh, const ushort* __restrict__ Xl,
    const float* __restrict__ G, const float* __restrict__ B,
    ushort* __restrict__ Zph, ushort* __restrict__ Zpl)
{
    const int g = blockIdx.x;          // n*T+t
    const int n = g / T_, t = g % T_;
    const float* p = P + (long)g * VC_;
    LN_STATS(p, VC_)
    const long pbase = ((long)(n * TP_ + t + 3) * V_) * C_;
    for (int i = threadIdx.x; i < VC_; i += 256) {
        long o = (long)g * VC_ + i;
        float xr = bf2f(Xh[o]) + bf2f(Xl[o]);
        float val = (p[i] - mean) * rstd * G[i] + B[i];
        float r = gelu_f(xr + val);
        ushort h = f2bf(r);
        Zph[pbase + i] = h;
        Zpl[pbase + i] = f2bf(r - bf2f(h));
    }
}

// ==============================================================================
extern "C" void kernel_launch(void* const* d_in, const int* in_sizes, int n_in,
                              void* d_out, int out_size, void* d_ws, size_t ws_size,
                              hipStream_t stream)
{
    const float* x        = (const float*)d_in[0];
    const float* Wqk_s    = (const float*)d_in[1];
    const float* bqk_s    = (const float*)d_in[2];
    const float* alphas   = (const float*)d_in[3];
    const float* att0s    = (const float*)d_in[4];
    const float* Wo_s     = (const float*)d_in[5];
    const float* bo_s     = (const float*)d_in[6];
    const float* g_os     = (const float*)d_in[7];
    const float* b_os     = (const float*)d_in[8];
    const float* Wff_s    = (const float*)d_in[9];
    const float* bff_s    = (const float*)d_in[10];
    const float* g_ffs    = (const float*)d_in[11];
    const float* b_ffs    = (const float*)d_in[12];
    const float* Wqk_t    = (const float*)d_in[13];
    const float* bqk_t    = (const float*)d_in[14];
    const float* alphat_f = (const float*)d_in[15];
    const float* alphat_b = (const float*)d_in[16];
    const float* Wo_t     = (const float*)d_in[17];
    const float* bo_t     = (const float*)d_in[18];
    const float* g_ot     = (const float*)d_in[19];
    const float* b_ot     = (const float*)d_in[20];
    const float* Wff_t    = (const float*)d_in[21];
    const float* bff_t    = (const float*)d_in[22];
    const float* g_fft    = (const float*)d_in[23];
    const float* b_fft    = (const float*)d_in[24];
    const float* conv_w   = (const float*)d_in[25];
    const float* conv_b   = (const float*)d_in[26];
    const float* bn_g     = (const float*)d_in[27];
    const float* bn_b     = (const float*)d_in[28];
    const float* bn_m     = (const float*)d_in[29];
    const float* bn_v     = (const float*)d_in[30];

    float* Bp  = (float*)d_ws;
    float* R0f = Bp;
    float* R1f = Bp + TOT_;
    float* R2f = Bp + 2 * TOT_;
    float* R3f = Bp + 3 * TOT_;
    float* SM  = Bp + 4 * TOT_;
    float* attPre = SM;                               // 60,000
    float* attS   = attPre + N_*V_*V_*S_;             // 60,000
    float* attF   = attS   + N_*V_*V_*S_;             // 262,144
    float* attB   = attF   + (long)N_*2*T_*T_;        // 262,144
    float* part   = attB   + (long)N_*2*T_*T_;        // 2,097,152
    ushort* wp = (ushort*)(part + 4L*N_*4*4096);
    ushort* qs_h = wp;  wp += 384*256;   ushort* qs_l = wp;  wp += 384*256;
    ushort* os_h = wp;  wp += 768*256;   ushort* os_l = wp;  wp += 768*256;
    ushort* fs_h = wp;  wp += 256*256;   ushort* fs_l = wp;  wp += 256*256;
    ushort* qt_h = wp;  wp += 512*256;   ushort* qt_l = wp;  wp += 512*256;
    ushort* ot0_h= wp;  wp += 512*256;   ushort* ot0_l= wp;  wp += 512*256;
    ushort* ot1_h= wp;  wp += 512*256;   ushort* ot1_l= wp;  wp += 512*256;
    ushort* ft_h = wp;  wp += 256*256;   ushort* ft_l = wp;  wp += 256*256;
    ushort* cv_h = wp;  wp += K_*256*256; ushort* cv_l = wp;

    // activation bf16 aliases (lifetimes annotated)
    ushort* xh  = (ushort*)R3f;  ushort* xl  = xh  + TOT_;   // until os GEMM
    ushort* Yh  = (ushort*)R0f;  ushort* Yl  = Yh  + TOT_;   // until fs GEMM
    ushort* YTh = (ushort*)d_out; ushort* YTl = YTh + TOT_;  // until ln_vc_z2
    ushort* QPh = (ushort*)R2f;  ushort* QPl = (ushort*)R3f; // until att_t_mfma
    ushort* Zh  = (ushort*)R0f;  ushort* Zl  = Zh  + TOT_;   // until ft GEMM
    ushort* Zph = (ushort*)R1f;                               // padded conv src
    ushort* Zpl = Zph + (long)N_ * TP_ * V_ * C_;

    // ---- preps (single weight launch + x planes) ----
    prep_weights<<<4992, 256, 0, stream>>>(
        Wqk_s, Wo_s, Wff_s, Wqk_t, Wo_t, Wff_t, conv_w,
        qs_h, qs_l, os_h, os_l, fs_h, fs_l, qt_h, qt_l,
        ot0_h, ot0_l, ot1_h, ot1_l, ft_h, ft_l, cv_h, cv_l);
    prep_x<<<(int)((TOT_ + 255)/256), 256, 0, stream>>>(x, xh, xl);

    // ---- Stage 1: spatial ----
    gemm_bf<<<dim3(3, 400), 256, 0, stream>>>(xh, xl, qs_h, qs_l, bqk_s, R0f, 384);
    zero_f32<<<(N_*V_*V_*S_ + 255)/256, 256, 0, stream>>>(attPre, N_*V_*V_*S_);
    att_s_partial<<<dim3(N_, 16), 256, 0, stream>>>(R0f, attPre);
    att_s_final<<<(N_*V_*V_*S_ + 255)/256, 256, 0, stream>>>(attPre, alphas, att0s, attS);
    gemm_bf<<<dim3(6, 400), 256, 0, stream>>>(xh, xl, os_h, os_l, nullptr, R0f, 768);
    vmix_all<<<dim3(T_, N_), 256, 0, stream>>>(R0f, attS, bo_s, R3f);
    ln_tc_y<<<N_*V_, 256, 0, stream>>>(R3f, x, g_os, b_os, Yh, Yl);
    gemm_bf<<<dim3(2, 400), 256, 0, stream>>>(Yh, Yl, fs_h, fs_l, bff_s, R1f, 256);
    ln_tc_yt<<<N_*V_, 256, 0, stream>>>(R1f, x, g_ffs, b_ffs, YTh, YTl);

    // ---- Stage 2: temporal ----
    gemm_bf<<<dim3(4, 400), 256, 0, stream>>>(YTh, YTl, qt_h, qt_l, bqk_t, R0f, 512);
    qkt_repack<<<(int)(((long)M_*CI_ + 255)/256), 256, 0, stream>>>(R0f, QPh, QPl);
    att_t_mfma<<<dim3(4, 4, N_), 256, 0, stream>>>(QPh, QPl, part);
    att_t_final<<<(N_*4*4096 + 255)/256, 256, 0, stream>>>(part, alphat_f, alphat_b, attF, attB);
    gemm_bf<<<dim3(4, 400), 256, 0, stream>>>(YTh, YTl, ot0_h, ot0_l, nullptr, R0f, 512);
    tmix_all<true><<<dim3(VC_/64, N_), 256, 0, stream>>>(R0f, attF, bo_t, R2f);
    gemm_bf<<<dim3(4, 400), 256, 0, stream>>>(YTh, YTl, ot1_h, ot1_l, nullptr, R0f, 512);
    tmix_all<false><<<dim3(VC_/64, N_), 256, 0, stream>>>(R0f, attB, nullptr, R2f);
    ln_vc_z<<<N_*T_, 256, 0, stream>>>(R2f, YTh, YTl, g_ot, b_ot, Zh, Zl);
    gemm_bf<<<dim3(2, 400), 256, 0, stream>>>(Zh, Zl, ft_h, ft_l, bff_t, R3f, 256);
    zero_pad<<<(N_*6*V_*C_ + 255)/256, 256, 0, stream>>>(Zph, Zpl);
    ln_vc_z2<<<N_*T_, 256, 0, stream>>>(R3f, YTh, YTl, g_fft, b_fft, Zph, Zpl);

    // ---- Stage 3: conv + BN + gelu + transpose ----
    conv_bn_gelu<<<dim3(2, 400), 256, 0, stream>>>(Zph, Zpl, cv_h, cv_l, conv_b, bn_g, bn_b, bn_m, bn_v, (float*)d_out);
}

// Round 12
// 1190.390 us; speedup vs baseline: 1.2598x; 1.0530x over previous
//
#include <hip/hip_runtime.h>

static constexpr int N_ = 32, V_ = 25, T_ = 64, C_ = 256;
static constexpr int S_ = 3, ST_ = 2, CI_ = 64, K_ = 7;
static constexpr int M_  = N_ * V_ * T_;          // 51200 rows (also N*T*V)
static constexpr int TC_ = T_ * C_;               // 16384
static constexpr int VC_ = V_ * C_;               // 6400
static constexpr long TOT_ = (long)M_ * C_;       // 13,107,200
static constexpr long PLANE_ = 2048L * 1600;      // per-chan QKT plane (ushorts)
static constexpr int TP_ = T_ + 6;                // padded t extent (70)
static constexpr int NOUT_ = V_ * V_ * S_;        // 1875

typedef __bf16 bf16x8 __attribute__((ext_vector_type(8)));
typedef float  f32x4  __attribute__((ext_vector_type(4)));

__device__ __forceinline__ float gelu_f(float x) {
    return 0.5f * x * (1.0f + erff(x * 0.70710678118654752f));
}
__device__ __forceinline__ ushort f2bf(float x) {       // RNE f32 -> bf16 bits
    uint u = __float_as_uint(x);
    u += 0x7fffu + ((u >> 16) & 1u);
    return (ushort)(u >> 16);
}
__device__ __forceinline__ float bf2f(ushort h) { return __uint_as_float((uint)h << 16); }

// split f32 x into hi/lo bf16 (4-wide)
__device__ __forceinline__ void split4(const float4& v, ushort4& h, ushort4& l) {
    h.x = f2bf(v.x); l.x = f2bf(v.x - bf2f(h.x));
    h.y = f2bf(v.y); l.y = f2bf(v.y - bf2f(h.y));
    h.z = f2bf(v.z); l.z = f2bf(v.z - bf2f(h.z));
    h.w = f2bf(v.w); l.w = f2bf(v.w - bf2f(h.w));
}

// physical LDS ushort offset for (row, chunk) with 2-way-free XOR swizzle
__device__ __forceinline__ int lofs(int row, int chunk) {
    return row * 32 + ((chunk ^ ((row >> 1) & 3)) << 3);
}

// async global->LDS 16B copy (LDS dest must be linear in lane order)
__device__ __forceinline__ void gll16(const ushort* g, ushort* l) {
    __builtin_amdgcn_global_load_lds(
        (const __attribute__((address_space(1))) void*)g,
        (__attribute__((address_space(3))) void*)l, 16, 0, 0);
}

// bijective XCD-chunked block swizzle (m204): same-XCD blocks get contiguous ids
__device__ __forceinline__ void xcd_swz(int& bx, int& by) {
    const int gx = gridDim.x;
    const int nwg = gx * gridDim.y;
    const int o = blockIdx.y * gx + blockIdx.x;
    const int q = nwg >> 3, r = nwg & 7;
    const int xcd = o & 7, idx = o >> 3;
    const int id = (xcd < r) ? (xcd * (q + 1) + idx)
                             : (r * (q + 1) + (xcd - r) * q + idx);
    bx = id % gx; by = id / gx;
}

// ---------------- preps --------------------------------------------------------
// all weight conversions in ONE launch (range-dispatched)
__global__ void prep_weights(
    const float* __restrict__ Wqk_s, const float* __restrict__ Wo_s,
    const float* __restrict__ Wff_s, const float* __restrict__ Wqk_t,
    const float* __restrict__ Wo_t,  const float* __restrict__ Wff_t,
    const float* __restrict__ conv_w,
    ushort* __restrict__ qs_h, ushort* __restrict__ qs_l,
    ushort* __restrict__ os_h, ushort* __restrict__ os_l,
    ushort* __restrict__ fs_h, ushort* __restrict__ fs_l,
    ushort* __restrict__ qt_h, ushort* __restrict__ qt_l,
    ushort* __restrict__ ot0_h, ushort* __restrict__ ot0_l,
    ushort* __restrict__ ot1_h, ushort* __restrict__ ot1_l,
    ushort* __restrict__ ft_h, ushort* __restrict__ ft_l,
    ushort* __restrict__ cv_h, ushort* __restrict__ cv_l)
{
    int idx = blockIdx.x * 256 + threadIdx.x;
    float x; ushort *h, *l; int li;
    if (idx < 819200) {
        // transposed [Nc][256] segments: plane[n][k] = W[k*LDW + n]
        const float* W; int base, ldw;
        if      (idx <  98304) { W=Wqk_s; h=qs_h;  l=qs_l;  base=0;      ldw=384; }
        else if (idx < 294912) { W=Wo_s;  h=os_h;  l=os_l;  base=98304;  ldw=768; }
        else if (idx < 360448) { W=Wff_s; h=fs_h;  l=fs_l;  base=294912; ldw=256; }
        else if (idx < 491520) { W=Wqk_t; h=qt_h;  l=qt_l;  base=360448; ldw=512; }
        else if (idx < 622592) { W=Wo_t;  h=ot0_h; l=ot0_l; base=491520; ldw=512; }
        else if (idx < 753664) { W=Wo_t + (long)ST_*C_*C_; h=ot1_h; l=ot1_l; base=622592; ldw=512; }
        else                   { W=Wff_t; h=ft_h;  l=ft_l;  base=753664; ldw=256; }
        li = idx - base;
        int n = li >> 8, k = li & 255;
        x = W[(long)k * ldw + n];
    } else {
        // conv: [kh][o][i] from cw (O,I,K)
        li = idx - 819200;                 // over K*C*C
        int kh = li / (C_ * C_);
        int rem = li % (C_ * C_);
        int o = rem >> 8, i = rem & 255;
        x = conv_w[((long)o * C_ + i) * K_ + kh];
        h = cv_h; l = cv_l;
    }
    ushort hb = f2bf(x);
    h[li] = hb;
    l[li] = f2bf(x - bf2f(hb));
}
// vectorized: 4 elems/thread, packed ushort4 stores
__global__ void prep_x(const float* __restrict__ X,
                       ushort* __restrict__ Xh, ushort* __restrict__ Xl) {
    long i = ((long)blockIdx.x * 256 + threadIdx.x) * 4;
    if (i >= TOT_) return;
    float4 v = *(const float4*)&X[i];
    ushort4 h, l;
    split4(v, h, l);
    *(ushort4*)&Xh[i] = h;
    *(ushort4*)&Xl[i] = l;
}
__global__ void zero_pad(ushort* __restrict__ Zph, ushort* __restrict__ Zpl) {
    int idx = blockIdx.x * 256 + threadIdx.x;        // over N*6*V*C
    if (idx >= N_ * 6 * V_ * C_) return;
    int n = idx / (6 * V_ * C_);
    int rem = idx % (6 * V_ * C_);
    int tpi = rem / (V_ * C_), vc = rem % (V_ * C_);
    int tp = (tpi < 3) ? tpi : (64 + tpi);           // 0,1,2,67,68,69
    long o = ((long)(n * TP_ + tp) * V_) * C_ + vc;
    Zph[o] = 0; Zpl[o] = 0;
}

// ---------------- bf16x3 MFMA GEMM: Out = A @ W (+bias), gll staging ----------
// R7 structure (measured best: conv 194us / MfmaUtil 30%): single-buffer LDS
// (32KB -> 3+ blocks/CU), gll for BOTH operands, 2 barriers per k-step.
// R8 (64KB dbuf) and R9 (global-W) both measured slower — do not repeat.
__global__ __launch_bounds__(256) void gemm_bf(
    const ushort* __restrict__ Agh, const ushort* __restrict__ Agl,
    const ushort* __restrict__ Wh,  const ushort* __restrict__ Wl,
    const float* __restrict__ bias,
    float* __restrict__ Out, int Nc)
{
    __shared__ ushort Ah[128 * 32], Al[128 * 32], Bh[128 * 32], Bl[128 * 32];
    int bx, by;  xcd_swz(bx, by);
    const int tid = threadIdx.x;
    const int row0 = by * 128, col0 = bx * 128;
    const int lane = tid & 63;
    const int wid = tid >> 6, wm = wid >> 1, wn = wid & 1;
    const int fr = lane & 15, fc = lane >> 4;
    // staging: unit u holds (row=u>>2, phys chunk=u&3); source uses logical chunk
    const int r0 = tid >> 2;
    const int cl0 = (tid & 3) ^ ((r0 >> 1) & 3);
    const int r1 = r0 + 64;
    const int cl1 = (tid & 3) ^ ((r1 >> 1) & 3);
    const long a0off = (long)(row0 + r0) * 256 + cl0 * 8;
    const long a1off = (long)(row0 + r1) * 256 + cl1 * 8;
    const long w0off = (long)(col0 + r0) * 256 + cl0 * 8;
    const long w1off = (long)(col0 + r1) * 256 + cl1 * 8;
    ushort* dA0 = &Ah[tid * 8];         ushort* dA1 = &Ah[(tid + 256) * 8];
    ushort* dL0 = &Al[tid * 8];         ushort* dL1 = &Al[(tid + 256) * 8];
    ushort* dB0 = &Bh[tid * 8];         ushort* dB1 = &Bh[(tid + 256) * 8];
    ushort* dM0 = &Bl[tid * 8];         ushort* dM1 = &Bl[(tid + 256) * 8];

    f32x4 acc[4][4] = {};
    for (int k0 = 0; k0 < 256; k0 += 32) {
        __syncthreads();
        gll16(Agh + a0off + k0, dA0);  gll16(Agh + a1off + k0, dA1);
        gll16(Agl + a0off + k0, dL0);  gll16(Agl + a1off + k0, dL1);
        gll16(Wh  + w0off + k0, dB0);  gll16(Wh  + w1off + k0, dB1);
        gll16(Wl  + w0off + k0, dM0);  gll16(Wl  + w1off + k0, dM1);
        __syncthreads();
        bf16x8 fah[4], fal[4];
        #pragma unroll
        for (int i = 0; i < 4; ++i) {
            int oA = lofs(wm * 64 + i * 16 + fr, fc);
            fah[i] = *(bf16x8*)&Ah[oA];
            fal[i] = *(bf16x8*)&Al[oA];
        }
        #pragma unroll
        for (int j = 0; j < 4; ++j) {
            int oW = lofs(wn * 64 + j * 16 + fr, fc);
            bf16x8 wh = *(bf16x8*)&Bh[oW];
            bf16x8 wl = *(bf16x8*)&Bl[oW];
            #pragma unroll
            for (int i = 0; i < 4; ++i) {
                acc[i][j] = __builtin_amdgcn_mfma_f32_16x16x32_bf16(fah[i], wh, acc[i][j], 0, 0, 0);
                acc[i][j] = __builtin_amdgcn_mfma_f32_16x16x32_bf16(fah[i], wl, acc[i][j], 0, 0, 0);
                acc[i][j] = __builtin_amdgcn_mfma_f32_16x16x32_bf16(fal[i], wh, acc[i][j], 0, 0, 0);
            }
        }
    }
    float bv[4]; int colv[4];
    #pragma unroll
    for (int j = 0; j < 4; ++j) {
        colv[j] = col0 + wn * 64 + j * 16 + fr;
        bv[j] = bias ? bias[colv[j]] : 0.0f;
    }
    #pragma unroll
    for (int i = 0; i < 4; ++i) {
        long rbase = row0 + wm * 64 + i * 16 + fc * 4;
        #pragma unroll
        for (int r = 0; r < 4; ++r) {
            long ob = (rbase + r) * (long)Nc;
            #pragma unroll
            for (int j = 0; j < 4; ++j)
                Out[ob + colv[j]] = acc[i][j][r] + bv[j];
        }
    }
}

// ---------------- conv(7x1 over T) bf16x3 MFMA from padded planes -------------
// R7 structure (single-buffer gll, measured ~192us).
__global__ __launch_bounds__(256) void conv_bn_gelu(
    const ushort* __restrict__ Zph, const ushort* __restrict__ Zpl, // (N,70,V,C)
    const ushort* __restrict__ Wh, const ushort* __restrict__ Wl,    // [kh][o][i]
    const float* __restrict__ conv_b, const float* __restrict__ bn_g,
    const float* __restrict__ bn_b,  const float* __restrict__ bn_m,
    const float* __restrict__ bn_v,
    float* __restrict__ Out)          // (N,V,T,C)
{
    __shared__ ushort Ah[128 * 32], Al[128 * 32], Bh[128 * 32], Bl[128 * 32];
    int bx, by;  xcd_swz(bx, by);
    const int tid = threadIdx.x;
    const int row0 = by * 128, col0 = bx * 128;
    const int lane = tid & 63;
    const int wid = tid >> 6, wm = wid >> 1, wn = wid & 1;
    const int fr = lane & 15, fc = lane >> 4;
    const int r0 = tid >> 2;
    const int cl0 = (tid & 3) ^ ((r0 >> 1) & 3);
    const int r1 = r0 + 64;
    const int cl1 = (tid & 3) ^ ((r1 >> 1) & 3);
    const int m0 = row0 + r0, m1 = row0 + r1;
    const int n0 = m0 / (T_ * V_), q0 = m0 % (T_ * V_);
    const int n1 = m1 / (T_ * V_), q1 = m1 % (T_ * V_);
    // padded base at tap 0 (t index t+0 in padded space = t-3 unpadded)
    const long a0base = ((long)(n0 * TP_ + q0 / V_) * V_ + q0 % V_) * 256 + cl0 * 8;
    const long a1base = ((long)(n1 * TP_ + q1 / V_) * V_ + q1 % V_) * 256 + cl1 * 8;
    const long w0base = (long)(col0 + r0) * 256 + cl0 * 8;
    const long w1base = (long)(col0 + r1) * 256 + cl1 * 8;
    ushort* dA0 = &Ah[tid * 8];         ushort* dA1 = &Ah[(tid + 256) * 8];
    ushort* dL0 = &Al[tid * 8];         ushort* dL1 = &Al[(tid + 256) * 8];
    ushort* dB0 = &Bh[tid * 8];         ushort* dB1 = &Bh[(tid + 256) * 8];
    ushort* dM0 = &Bl[tid * 8];         ushort* dM1 = &Bl[(tid + 256) * 8];

    f32x4 acc[4][4] = {};
    for (int kt = 0; kt < K_ * 8; ++kt) {     // 56 k-steps of 32
        const int kh = kt >> 3;
        const long kc = (kt & 7) * 32;
        const long ao = (long)kh * V_ * 256;
        const long wo = (long)kh * 65536 + kc;
        __syncthreads();
        gll16(Zph + a0base + ao + kc, dA0);  gll16(Zph + a1base + ao + kc, dA1);
        gll16(Zpl + a0base + ao + kc, dL0);  gll16(Zpl + a1base + ao + kc, dL1);
        gll16(Wh + w0base + wo, dB0);        gll16(Wh + w1base + wo, dB1);
        gll16(Wl + w0base + wo, dM0);        gll16(Wl + w1base + wo, dM1);
        __syncthreads();
        bf16x8 fah[4], fal[4];
        #pragma unroll
        for (int i = 0; i < 4; ++i) {
            int oA = lofs(wm * 64 + i * 16 + fr, fc);
            fah[i] = *(bf16x8*)&Ah[oA];
            fal[i] = *(bf16x8*)&Al[oA];
        }
        #pragma unroll
        for (int j = 0; j < 4; ++j) {
            int oW = lofs(wn * 64 + j * 16 + fr, fc);
            bf16x8 wh = *(bf16x8*)&Bh[oW];
            bf16x8 wl = *(bf16x8*)&Bl[oW];
            #pragma unroll
            for (int i = 0; i < 4; ++i) {
                acc[i][j] = __builtin_amdgcn_mfma_f32_16x16x32_bf16(fah[i], wh, acc[i][j], 0, 0, 0);
                acc[i][j] = __builtin_amdgcn_mfma_f32_16x16x32_bf16(fah[i], wl, acc[i][j], 0, 0, 0);
                acc[i][j] = __builtin_amdgcn_mfma_f32_16x16x32_bf16(fal[i], wh, acc[i][j], 0, 0, 0);
            }
        }
    }
    float cbv[4], scv[4], shv[4]; int colv[4];
    #pragma unroll
    for (int j = 0; j < 4; ++j) {
        int c = col0 + wn * 64 + j * 16 + fr;
        colv[j] = c;
        cbv[j] = conv_b[c];
        float sc = rsqrtf(bn_v[c] + 1e-5f) * bn_g[c];
        scv[j] = sc;
        shv[j] = bn_b[c] - bn_m[c] * sc;
    }
    #pragma unroll
    for (int i = 0; i < 4; ++i)
        #pragma unroll
        for (int r = 0; r < 4; ++r) {
            int m = row0 + wm * 64 + i * 16 + fc * 4 + r;
            int n = m / (T_ * V_);
            int rem = m % (T_ * V_);
            int t = rem / V_, v = rem % V_;
            long ob = (((long)n * V_ + v) * T_ + t) * C_;
            long pb = ((long)(n * TP_ + t + 3) * V_ + v) * C_;   // residual from planes
            #pragma unroll
            for (int j = 0; j < 4; ++j) {
                float cv = acc[i][j][r] + cbv[j];
                float bn = cv * scv[j] + shv[j];
                float res = bf2f(Zph[pb + colv[j]]) + bf2f(Zpl[pb + colv[j]]);
                Out[ob + colv[j]] = gelu_f(res + bn);
            }
        }
}

// ---------------- spatial attention scores ------------------------------------
// per-tg partial writes (no atomics, no zero pass)
__global__ __launch_bounds__(256) void att_s_partial(
    const float* __restrict__ QK,     // (N,V,T,384)
    float* __restrict__ attPre2)      // (N,16,NOUT)
{
    const int n = blockIdx.x;
    const int tg = blockIdx.y;        // 0..15, 4 t's each
    __shared__ float lds[V_ * 385];   // odd stride: no bank alias
    float acc[8] = {};
    for (int ttc = 0; ttc < 4; ++ttc) {
        int t = tg * 4 + ttc;
        __syncthreads();
        for (int l = threadIdx.x; l < V_ * 96; l += 256) {
            int v = l / 96, j = (l % 96) * 4;
            float4 q = *(const float4*)&QK[(((long)n * V_ + v) * T_ + t) * 384 + j];
            float* d = &lds[v * 385 + j];
            d[0] = q.x; d[1] = q.y; d[2] = q.z; d[3] = q.w;
        }
        __syncthreads();
        int ai = 0;
        for (int o = threadIdx.x; o < NOUT_; o += 256, ++ai) {
            int u = o / (V_ * S_), rem = o % (V_ * S_), v = rem / S_, s = rem % S_;
            const float* qp = &lds[u * 385 + s];
            const float* kp = &lds[v * 385 + S_ + s];
            float sum = 0.f;
            #pragma unroll 8
            for (int ci = 0; ci < CI_; ++ci) sum += qp[ci * 6] * kp[ci * 6];
            acc[ai] += sum;
        }
    }
    float* pb = attPre2 + ((long)n * 16 + tg) * NOUT_;
    int ai = 0;
    for (int o = threadIdx.x; o < NOUT_; o += 256, ++ai)
        pb[o] = acc[ai];
}

__global__ void att_s_final(const float* __restrict__ attPre2,
                            const float* __restrict__ alphas,
                            const float* __restrict__ att0,
                            float* __restrict__ attS) {
    int idx = blockIdx.x * 256 + threadIdx.x;
    if (idx >= N_ * NOUT_) return;
    int n = idx / NOUT_, o = idx % NOUT_;
    int s = o % S_;
    const float* pb = attPre2 + (long)n * 16 * NOUT_ + o;
    float sum = 0.f;
    #pragma unroll
    for (int g = 0; g < 16; ++g) sum += pb[(long)g * NOUT_];
    attS[idx] = tanhf(sum * (1.0f / (CI_ * T_))) * alphas[s] + att0[o];
}

// ---------------- fused spatial mixing ----------------------------------------
__global__ __launch_bounds__(256) void vmix_all(
    const float* __restrict__ G,      // (M, 768)
    const float* __restrict__ attS,   // (N,V,V,S)
    const float* __restrict__ bias,   // (C)
    float* __restrict__ P)            // (N,V,TC)
{
    const int n = blockIdx.y;
    const int t = blockIdx.x;         // 0..63
    const int c = threadIdx.x;        // 0..255
    __shared__ float a[3][V_ * V_];
    for (int l = threadIdx.x; l < V_ * V_ * S_; l += 256) {
        int uv = l / S_, s = l % S_;
        a[s][uv] = attS[((long)n * V_ * V_ + uv) * S_ + s];
    }
    __syncthreads();
    float acc[V_] = {};
    for (int u = 0; u < V_; ++u) {
        const float* g = G + ((long)((n * V_ + u) * T_) + t) * 768 + c;
        float v0 = g[0], v1 = g[256], v2 = g[512];
        const float* a0 = &a[0][u * V_], *a1 = &a[1][u * V_], *a2 = &a[2][u * V_];
        #pragma unroll
        for (int v = 0; v < V_; ++v)
            acc[v] += a0[v] * v0 + a1[v] * v1 + a2[v] * v2;
    }
    const float b = bias[c];
    for (int v = 0; v < V_; ++v)
        P[((long)(n * V_ + v) * T_ + t) * C_ + c] = acc[v] + b;
}

// ---------------- QKT repack: (N,T,V,ci,8chan) f32 -> 8 k-major bf16 planes ---
__global__ void qkt_repack(const float* __restrict__ QKT,
                           ushort* __restrict__ QPh, ushort* __restrict__ QPl) {
    long idx = (long)blockIdx.x * 256 + threadIdx.x;   // over M_*CI_
    if (idx >= (long)M_ * CI_) return;
    int m = (int)(idx >> 6), ci = (int)(idx & 63);
    int n = m / (T_ * V_);
    int rem = m % (T_ * V_);
    int t = rem / V_, v = rem % V_;
    const float* src = QKT + (long)m * 512 + ci * 8;
    float4 s0 = *(const float4*)src;
    float4 s1 = *(const float4*)(src + 4);
    float f[8] = {s0.x, s0.y, s0.z, s0.w, s1.x, s1.y, s1.z, s1.w};
    long rowk = ((long)(n * T_ + t)) * 1600 + v * 64 + ci;
    #pragma unroll
    for (int chan = 0; chan < 8; ++chan) {
        ushort h = f2bf(f[chan]);
        QPh[(long)chan * PLANE_ + rowk] = h;
        QPl[(long)chan * PLANE_ + rowk] = f2bf(f[chan] - bf2f(h));
    }
}

// ---------------- temporal attention scores via bf16x3 MFMA -------------------
__global__ __launch_bounds__(256) void att_t_mfma(
    const ushort* __restrict__ QPh, const ushort* __restrict__ QPl,
    float* __restrict__ part)
{
    const int ks = blockIdx.x, pair = blockIdx.y, n = blockIdx.z;
    const int kbeg = (ks * 50) / 4, kend = ((ks + 1) * 50) / 4;   // 50 k-steps of 32
    __shared__ ushort Qh[64 * 32], Ql[64 * 32], Kh[64 * 32], Kl[64 * 32];
    const int tid = threadIdx.x;
    const int lane = tid & 63;
    const int wid = tid >> 6, wm = wid >> 1, wn = wid & 1;
    const int fr = lane & 15, fc = lane >> 4;
    const int tr = tid >> 2, tc = tid & 3;
    const long rowoff = ((long)n * T_ + tr) * 1600 + tc * 8;
    const ushort* qh_g = QPh + (long)pair * PLANE_ + rowoff;
    const ushort* ql_g = QPl + (long)pair * PLANE_ + rowoff;
    const ushort* kh_g = QPh + (long)(pair + 4) * PLANE_ + rowoff;
    const ushort* kl_g = QPl + (long)(pair + 4) * PLANE_ + rowoff;
    const int la = lofs(tr, tc);

    uint4 pqh = *(const uint4*)(qh_g + kbeg * 32);
    uint4 pql = *(const uint4*)(ql_g + kbeg * 32);
    uint4 pkh = *(const uint4*)(kh_g + kbeg * 32);
    uint4 pkl = *(const uint4*)(kl_g + kbeg * 32);

    f32x4 acc[2][2] = {};
    for (int kstep = kbeg; kstep < kend; ++kstep) {
        __syncthreads();
        *(uint4*)&Qh[la] = pqh;  *(uint4*)&Ql[la] = pql;
        *(uint4*)&Kh[la] = pkh;  *(uint4*)&Kl[la] = pkl;
        __syncthreads();
        if (kstep + 1 < kend) {
            pqh = *(const uint4*)(qh_g + (kstep + 1) * 32);
            pql = *(const uint4*)(ql_g + (kstep + 1) * 32);
            pkh = *(const uint4*)(kh_g + (kstep + 1) * 32);
            pkl = *(const uint4*)(kl_g + (kstep + 1) * 32);
        }
        bf16x8 ah[2], al[2];
        #pragma unroll
        for (int i = 0; i < 2; ++i) {
            int oA = lofs(wm * 32 + i * 16 + fr, fc);
            ah[i] = *(bf16x8*)&Qh[oA];
            al[i] = *(bf16x8*)&Ql[oA];
        }
        #pragma unroll
        for (int j = 0; j < 2; ++j) {
            int oB = lofs(wn * 32 + j * 16 + fr, fc);
            bf16x8 bh = *(bf16x8*)&Kh[oB];
            bf16x8 bl = *(bf16x8*)&Kl[oB];
            #pragma unroll
            for (int i = 0; i < 2; ++i) {
                acc[i][j] = __builtin_amdgcn_mfma_f32_16x16x32_bf16(ah[i], bh, acc[i][j], 0, 0, 0);
                acc[i][j] = __builtin_amdgcn_mfma_f32_16x16x32_bf16(ah[i], bl, acc[i][j], 0, 0, 0);
                acc[i][j] = __builtin_amdgcn_mfma_f32_16x16x32_bf16(al[i], bh, acc[i][j], 0, 0, 0);
            }
        }
    }
    float* pb = part + (((long)ks * N_ + n) * 4 + pair) * 4096;
    #pragma unroll
    for (int i = 0; i < 2; ++i)
        #pragma unroll
        for (int r = 0; r < 4; ++r) {
            int t = wm * 32 + i * 16 + fc * 4 + r;
            #pragma unroll
            for (int j = 0; j < 2; ++j) {
                int q = wn * 32 + j * 16 + fr;
                pb[t * 64 + q] = acc[i][j][r];
            }
        }
}

// ---------------- finish temporal attention -----------------------------------
__global__ void att_t_final(const float* __restrict__ part,
                            const float* __restrict__ alphat_f,
                            const float* __restrict__ alphat_b,
                            float* __restrict__ attF, float* __restrict__ attB) {
    int idx = blockIdx.x * 256 + threadIdx.x;   // N*4*4096
    if (idx >= N_ * 4 * 4096) return;
    int n = idx >> 14;
    int rem = idx & 16383;
    int p = rem >> 12, tq = rem & 4095;
    int t = tq >> 6, q = tq & 63;
    const long stride = (long)N_ * 4 * 4096;
    float sum = 0.f;
    #pragma unroll
    for (int ks = 0; ks < 4; ++ks) sum += part[ks * stride + idx];
    float val = tanhf(sum * (1.0f / (CI_ * V_)));
    if (p < 2) {
        float m = (t >= q) ? 1.0f : 0.0f;
        attF[((long)(n * 2 + p)) * 4096 + tq] = val * alphat_f[p] * m;
    } else {
        float m = (q >= t) ? 1.0f : 0.0f;
        attB[((long)(n * 2 + (p - 2))) * 4096 + tq] = val * alphat_b[p - 2] * m;
    }
}

// ---------------- fused temporal mixing ---------------------------------------
template <bool INIT>
__global__ __launch_bounds__(256) void tmix_all(
    const float* __restrict__ G,      // (M, 512) rows (n*T+t)*V+v
    const float* __restrict__ att,    // (N,2,T,T)
    const float* __restrict__ bias,   // (C) or null
    float* __restrict__ P)            // (N,T,VC)
{
    const int n = blockIdx.y;
    const int col = blockIdx.x * 64 + (threadIdx.x & 63);  // 0..VC-1
    const int ty = threadIdx.x >> 6;                       // 0..3
    const int v = col >> 8, c = col & 255;
    __shared__ float a[2 * T_ * T_];
    for (int l = threadIdx.x; l < 2 * T_ * T_; l += 256)
        a[l] = att[(long)n * 2 * T_ * T_ + l];
    __syncthreads();
    float acc[16] = {};
    for (int t = 0; t < T_; ++t) {
        const float* g = G + ((long)((n * T_ + t) * V_) + v) * 512 + c;
        float v0 = g[0], v1 = g[256];
        const float* ar0 = &a[t * T_ + ty * 16];
        const float* ar1 = ar0 + T_ * T_;
        #pragma unroll
        for (int i = 0; i < 16; ++i) acc[i] += ar0[i] * v0 + ar1[i] * v1;
    }
    for (int i = 0; i < 16; ++i) {
        int q = ty * 16 + i;
        long idx = ((long)n * T_ + q) * VC_ + col;
        if (INIT) P[idx] = acc[i] + bias[c];
        else      P[idx] += acc[i];
    }
}

// ---------------- LayerNorm kernels (vectorized: float4 in, ushort4 out) ------
#define LN_STATS4(PBASE, L)                                                    \
    float s = 0.f, ss = 0.f;                                                   \
    for (int i4 = threadIdx.x * 4; i4 < (L); i4 += 1024) {                     \
        float4 a = *(const float4*)&(PBASE)[i4];                               \
        s += a.x + a.y + a.z + a.w;                                            \
        ss += a.x * a.x + a.y * a.y + a.z * a.z + a.w * a.w; }                 \
    __shared__ float rs[4], rss[4];                                            \
    _Pragma("unroll")                                                          \
    for (int off = 32; off > 0; off >>= 1) { s += __shfl_down(s, off); ss += __shfl_down(ss, off); } \
    if ((threadIdx.x & 63) == 0) { rs[threadIdx.x >> 6] = s; rss[threadIdx.x >> 6] = ss; } \
    __syncthreads();                                                           \
    s = rs[0] + rs[1] + rs[2] + rs[3];                                         \
    ss = rss[0] + rss[1] + rss[2] + rss[3];                                    \
    const float mean = s * (1.0f / (L));                                       \
    const float var  = ss * (1.0f / (L)) - mean * mean;                        \
    const float rstd = rsqrtf(var + 1e-5f);

__device__ __forceinline__ float4 ln_body4(const float4& pv, const float4& xv,
                                           const float4& gv, const float4& bv,
                                           float mean, float rstd) {
    float4 r;
    r.x = gelu_f(xv.x + (pv.x - mean) * rstd * gv.x + bv.x);
    r.y = gelu_f(xv.y + (pv.y - mean) * rstd * gv.y + bv.y);
    r.z = gelu_f(xv.z + (pv.z - mean) * rstd * gv.z + bv.z);
    r.w = gelu_f(xv.w + (pv.w - mean) * rstd * gv.w + bv.w);
    return r;
}

// Y = gelu(x + ln(P)) over (T,C) -> bf16 hi/lo, same layout
__global__ __launch_bounds__(256) void ln_tc_y(
    const float* __restrict__ P, const float* __restrict__ X,
    const float* __restrict__ G, const float* __restrict__ B,
    ushort* __restrict__ Oh, ushort* __restrict__ Ol)
{
    const int g = blockIdx.x;          // n*V+v
    const float* p = P + (long)g * TC_;
    const float* x = X + (long)g * TC_;
    LN_STATS4(p, TC_)
    for (int i = threadIdx.x * 4; i < TC_; i += 1024) {
        float4 pv = *(const float4*)&p[i];
        float4 xv = *(const float4*)&x[i];
        float4 gv = *(const float4*)&G[i];
        float4 bv = *(const float4*)&B[i];
        float4 r = ln_body4(pv, xv, gv, bv, mean, rstd);
        ushort4 h, l;
        split4(r, h, l);
        *(ushort4*)&Oh[(long)g * TC_ + i] = h;
        *(ushort4*)&Ol[(long)g * TC_ + i] = l;
    }
}

// YT = gelu(x + ln(P)) over (T,C), transposed to (N,T,V,C) -> bf16 hi/lo ONLY
__global__ __launch_bounds__(256) void ln_tc_yt(
    const float* __restrict__ P, const float* __restrict__ X,
    const float* __restrict__ G, const float* __restrict__ B,
    ushort* __restrict__ Oh, ushort* __restrict__ Ol)
{
    const int g = blockIdx.x;          // n*V+v
    const int n = g / V_, v = g % V_;
    const float* p = P + (long)g * TC_;
    const float* x = X + (long)g * TC_;
    LN_STATS4(p, TC_)
    for (int i = threadIdx.x * 4; i < TC_; i += 1024) {
        float4 pv = *(const float4*)&p[i];
        float4 xv = *(const float4*)&x[i];
        float4 gv = *(const float4*)&G[i];
        float4 bv = *(const float4*)&B[i];
        float4 r = ln_body4(pv, xv, gv, bv, mean, rstd);
        int t = i >> 8, c = i & 255;
        long o = (((long)n * T_ + t) * V_ + v) * C_ + c;
        ushort4 h, l;
        split4(r, h, l);
        *(ushort4*)&Oh[o] = h;
        *(ushort4*)&Ol[o] = l;
    }
}

// Z = gelu(yT + ln(P)) over (V,C), residual from YT planes -> bf16 hi/lo
__global__ __launch_bounds__(256) void ln_vc_z(
    const float* __restrict__ P,
    const ushort* __restrict__ Xh, const ushort* __restrict__ Xl,
    const float* __restrict__ G, const float* __restrict__ B,
    ushort* __restrict__ Oh, ushort* __restrict__ Ol)
{
    const int g = blockIdx.x;          // n*T+t
    const float* p = P + (long)g * VC_;
    LN_STATS4(p, VC_)
    for (int i = threadIdx.x * 4; i < VC_; i += 1024) {
        long o = (long)g * VC_ + i;
        float4 pv = *(const float4*)&p[i];
        ushort4 xh4 = *(const ushort4*)&Xh[o];
        ushort4 xl4 = *(const ushort4*)&Xl[o];
        float4 xv;
        xv.x = bf2f(xh4.x) + bf2f(xl4.x);
        xv.y = bf2f(xh4.y) + bf2f(xl4.y);
        xv.z = bf2f(xh4.z) + bf2f(xl4.z);
        xv.w = bf2f(xh4.w) + bf2f(xl4.w);
        float4 gv = *(const float4*)&G[i];
        float4 bv = *(const float4*)&B[i];
        float4 r = ln_body4(pv, xv, gv, bv, mean, rstd);
        ushort4 h, l;
        split4(r, h, l);
        *(ushort4*)&Oh[o] = h;
        *(ushort4*)&Ol[o] = l;
    }
}

// Z2 = gelu(yT + ln(P)) over (V,C), residual from YT planes -> padded planes
__global__ __launch_bounds__(256) void ln_vc_z2(
    const float* __restrict__ P,
    const ushort* __restrict__ Xh, const ushort* __restrict__ Xl,
    const float* __restrict__ G, const float* __restrict__ B,
    ushort* __restrict__ Zph, ushort* __restrict__ Zpl)
{
    const int g = blockIdx.x;          // n*T+t
    const int n = g / T_, t = g % T_;
    const float* p = P + (long)g * VC_;
    LN_STATS4(p, VC_)
    const long pbase = ((long)(n * TP_ + t + 3) * V_) * C_;
    for (int i = threadIdx.x * 4; i < VC_; i += 1024) {
        long o = (long)g * VC_ + i;
        float4 pv = *(const float4*)&p[i];
        ushort4 xh4 = *(const ushort4*)&Xh[o];
        ushort4 xl4 = *(const ushort4*)&Xl[o];
        float4 xv;
        xv.x = bf2f(xh4.x) + bf2f(xl4.x);
        xv.y = bf2f(xh4.y) + bf2f(xl4.y);
        xv.z = bf2f(xh4.z) + bf2f(xl4.z);
        xv.w = bf2f(xh4.w) + bf2f(xl4.w);
        float4 gv = *(const float4*)&G[i];
        float4 bv = *(const float4*)&B[i];
        float4 r = ln_body4(pv, xv, gv, bv, mean, rstd);
        ushort4 h, l;
        split4(r, h, l);
        *(ushort4*)&Zph[pbase + i] = h;
        *(ushort4*)&Zpl[pbase + i] = l;
    }
}

// ==============================================================================
extern "C" void kernel_launch(void* const* d_in, const int* in_sizes, int n_in,
                              void* d_out, int out_size, void* d_ws, size_t ws_size,
                              hipStream_t stream)
{
    const float* x        = (const float*)d_in[0];
    const float* Wqk_s    = (const float*)d_in[1];
    const float* bqk_s    = (const float*)d_in[2];
    const float* alphas   = (const float*)d_in[3];
    const float* att0s    = (const float*)d_in[4];
    const float* Wo_s     = (const float*)d_in[5];
    const float* bo_s     = (const float*)d_in[6];
    const float* g_os     = (const float*)d_in[7];
    const float* b_os     = (const float*)d_in[8];
    const float* Wff_s    = (const float*)d_in[9];
    const float* bff_s    = (const float*)d_in[10];
    const float* g_ffs    = (const float*)d_in[11];
    const float* b_ffs    = (const float*)d_in[12];
    const float* Wqk_t    = (const float*)d_in[13];
    const float* bqk_t    = (const float*)d_in[14];
    const float* alphat_f = (const float*)d_in[15];
    const float* alphat_b = (const float*)d_in[16];
    const float* Wo_t     = (const float*)d_in[17];
    const float* bo_t     = (const float*)d_in[18];
    const float* g_ot     = (const float*)d_in[19];
    const float* b_ot     = (const float*)d_in[20];
    const float* Wff_t    = (const float*)d_in[21];
    const float* bff_t    = (const float*)d_in[22];
    const float* g_fft    = (const float*)d_in[23];
    const float* b_fft    = (const float*)d_in[24];
    const float* conv_w   = (const float*)d_in[25];
    const float* conv_b   = (const float*)d_in[26];
    const float* bn_g     = (const float*)d_in[27];
    const float* bn_b     = (const float*)d_in[28];
    const float* bn_m     = (const float*)d_in[29];
    const float* bn_v     = (const float*)d_in[30];

    float* Bp  = (float*)d_ws;
    float* R0f = Bp;
    float* R1f = Bp + TOT_;
    float* R2f = Bp + 2 * TOT_;
    float* R3f = Bp + 3 * TOT_;
    float* SM  = Bp + 4 * TOT_;
    float* attPre2 = SM;                               // N*16*NOUT = 960,000
    float* attS   = attPre2 + (long)N_*16*NOUT_;       // 60,000
    float* attF   = attS   + N_*NOUT_;                 // 262,144
    float* attB   = attF   + (long)N_*2*T_*T_;         // 262,144
    float* part   = attB   + (long)N_*2*T_*T_;         // 2,097,152
    ushort* wp = (ushort*)(part + 4L*N_*4*4096);
    ushort* qs_h = wp;  wp += 384*256;   ushort* qs_l = wp;  wp += 384*256;
    ushort* os_h = wp;  wp += 768*256;   ushort* os_l = wp;  wp += 768*256;
    ushort* fs_h = wp;  wp += 256*256;   ushort* fs_l = wp;  wp += 256*256;
    ushort* qt_h = wp;  wp += 512*256;   ushort* qt_l = wp;  wp += 512*256;
    ushort* ot0_h= wp;  wp += 512*256;   ushort* ot0_l= wp;  wp += 512*256;
    ushort* ot1_h= wp;  wp += 512*256;   ushort* ot1_l= wp;  wp += 512*256;
    ushort* ft_h = wp;  wp += 256*256;   ushort* ft_l = wp;  wp += 256*256;
    ushort* cv_h = wp;  wp += K_*256*256; ushort* cv_l = wp;

    // activation bf16 aliases (lifetimes annotated)
    ushort* xh  = (ushort*)R3f;  ushort* xl  = xh  + TOT_;   // until os GEMM
    ushort* Yh  = (ushort*)R0f;  ushort* Yl  = Yh  + TOT_;   // until fs GEMM
    ushort* YTh = (ushort*)d_out; ushort* YTl = YTh + TOT_;  // until ln_vc_z2
    ushort* QPh = (ushort*)R2f;  ushort* QPl = (ushort*)R3f; // until att_t_mfma
    ushort* Zh  = (ushort*)R0f;  ushort* Zl  = Zh  + TOT_;   // until ft GEMM
    ushort* Zph = (ushort*)R1f;                               // padded conv src
    ushort* Zpl = Zph + (long)N_ * TP_ * V_ * C_;

    // ---- preps (single weight launch + x planes) ----
    prep_weights<<<4992, 256, 0, stream>>>(
        Wqk_s, Wo_s, Wff_s, Wqk_t, Wo_t, Wff_t, conv_w,
        qs_h, qs_l, os_h, os_l, fs_h, fs_l, qt_h, qt_l,
        ot0_h, ot0_l, ot1_h, ot1_l, ft_h, ft_l, cv_h, cv_l);
    prep_x<<<(int)((TOT_/4 + 255)/256), 256, 0, stream>>>(x, xh, xl);

    // ---- Stage 1: spatial ----
    gemm_bf<<<dim3(3, 400), 256, 0, stream>>>(xh, xl, qs_h, qs_l, bqk_s, R0f, 384);
    att_s_partial<<<dim3(N_, 16), 256, 0, stream>>>(R0f, attPre2);
    att_s_final<<<(N_*NOUT_ + 255)/256, 256, 0, stream>>>(attPre2, alphas, att0s, attS);
    gemm_bf<<<dim3(6, 400), 256, 0, stream>>>(xh, xl, os_h, os_l, nullptr, R0f, 768);
    vmix_all<<<dim3(T_, N_), 256, 0, stream>>>(R0f, attS, bo_s, R3f);
    ln_tc_y<<<N_*V_, 256, 0, stream>>>(R3f, x, g_os, b_os, Yh, Yl);
    gemm_bf<<<dim3(2, 400), 256, 0, stream>>>(Yh, Yl, fs_h, fs_l, bff_s, R1f, 256);
    ln_tc_yt<<<N_*V_, 256, 0, stream>>>(R1f, x, g_ffs, b_ffs, YTh, YTl);

    // ---- Stage 2: temporal ----
    gemm_bf<<<dim3(4, 400), 256, 0, stream>>>(YTh, YTl, qt_h, qt_l, bqk_t, R0f, 512);
    qkt_repack<<<(int)(((long)M_*CI_ + 255)/256), 256, 0, stream>>>(R0f, QPh, QPl);
    att_t_mfma<<<dim3(4, 4, N_), 256, 0, stream>>>(QPh, QPl, part);
    att_t_final<<<(N_*4*4096 + 255)/256, 256, 0, stream>>>(part, alphat_f, alphat_b, attF, attB);
    gemm_bf<<<dim3(4, 400), 256, 0, stream>>>(YTh, YTl, ot0_h, ot0_l, nullptr, R0f, 512);
    tmix_all<true><<<dim3(VC_/64, N_), 256, 0, stream>>>(R0f, attF, bo_t, R2f);
    gemm_bf<<<dim3(4, 400), 256, 0, stream>>>(YTh, YTl, ot1_h, ot1_l, nullptr, R0f, 512);
    tmix_all<false><<<dim3(VC_/64, N_), 256, 0, stream>>>(R0f, attB, nullptr, R2f);
    ln_vc_z<<<N_*T_, 256, 0, stream>>>(R2f, YTh, YTl, g_ot, b_ot, Zh, Zl);
    gemm_bf<<<dim3(2, 400), 256, 0, stream>>>(Zh, Zl, ft_h, ft_l, bff_t, R3f, 256);
    zero_pad<<<(N_*6*V_*C_ + 255)/256, 256, 0, stream>>>(Zph, Zpl);
    ln_vc_z2<<<N_*T_, 256, 0, stream>>>(R3f, YTh, YTl, g_fft, b_fft, Zph, Zpl);

    // ---- Stage 3: conv + BN + gelu + transpose ----
    conv_bn_gelu<<<dim3(2, 400), 256, 0, stream>>>(Zph, Zpl, cv_h, cv_l, conv_b, bn_g, bn_b, bn_m, bn_v, (float*)d_out);
}